// Round 1
// 2437.368 us; speedup vs baseline: 2.8684x; 2.8684x over previous
//
#include <hip/hip_runtime.h>
#include <hip/hip_bf16.h>

#define Bc 64
#define Nn 1029
#define Dd 768
#define Hh 12
#define DH 64
#define Kk 128
#define Rr 5
#define Mm 4
#define Pp 1024
#define CTX 133
#define TWO_D 1536

typedef unsigned short u16;
typedef __attribute__((ext_vector_type(8))) short bf16x8;   // 8 bf16 = 4 VGPRs
typedef __attribute__((ext_vector_type(4))) float f32x4;

__device__ __forceinline__ float bs2f(u16 u){
    union { unsigned int i; float f; } c; c.i = ((unsigned)u) << 16; return c.f;
}
__device__ __forceinline__ u16 f2bs(float f){
    unsigned int u = __float_as_uint(f);
    unsigned int r = (u + 0x7fffu + ((u >> 16) & 1u)) >> 16;  // RNE
    return (u16)r;
}

#define FMA16(acc, a, b4) do { \
    acc[0][0] += a.x*b4.x; acc[0][1] += a.x*b4.y; acc[0][2] += a.x*b4.z; acc[0][3] += a.x*b4.w; \
    acc[1][0] += a.y*b4.x; acc[1][1] += a.y*b4.y; acc[1][2] += a.y*b4.z; acc[1][3] += a.y*b4.w; \
    acc[2][0] += a.z*b4.x; acc[2][1] += a.z*b4.y; acc[2][2] += a.z*b4.z; acc[2][3] += a.z*b4.w; \
    acc[3][0] += a.w*b4.x; acc[3][1] += a.w*b4.y; acc[3][2] += a.w*b4.z; acc[3][3] += a.w*b4.w; \
} while(0)

// ---------------- K1: cls_n + argmax idx ----------------
__global__ __launch_bounds__(256)
void k_cls(const float* __restrict__ x, const float* __restrict__ cent,
           float* __restrict__ out_cls, float* __restrict__ out_idx,
           int* __restrict__ idx_i)
{
    int b = blockIdx.x, t = threadIdx.x;
    const float* xr = x + (size_t)b * Nn * Dd;
    __shared__ float sx[Dd];
    __shared__ float wred[4];
    float ss = 0.f;
    for (int i = t; i < Dd; i += 256) { float v = xr[i]; sx[i] = v; ss += v * v; }
    for (int o = 32; o > 0; o >>= 1) ss += __shfl_down(ss, o);
    int lane = t & 63, wid = t >> 6;
    if (lane == 0) wred[wid] = ss;
    __syncthreads();
    float tot = wred[0] + wred[1] + wred[2] + wred[3];
    float inv = 1.f / fmaxf(sqrtf(tot), 1e-12f);
    __syncthreads();
    for (int i = t; i < Dd; i += 256) { float v = sx[i] * inv; sx[i] = v; out_cls[(size_t)b * Dd + i] = v; }
    __syncthreads();
    float sm[Mm];
    for (int m = 0; m < Mm; m++) {
        float s = 0.f;
        for (int i = t; i < Dd; i += 256) s += sx[i] * cent[m * Dd + i];
        for (int o = 32; o > 0; o >>= 1) s += __shfl_down(s, o);
        __syncthreads();
        if (lane == 0) wred[wid] = s;
        __syncthreads();
        sm[m] = wred[0] + wred[1] + wred[2] + wred[3];
    }
    if (t == 0) {
        int best = 0; float bv = sm[0];
        for (int m = 1; m < Mm; m++) if (sm[m] > bv) { bv = sm[m]; best = m; }
        idx_i[b] = best;
        out_idx[b] = (float)best;
    }
}

// ---------------- K2: scores = Q_banks[idx] @ xp^T  (NT GEMM, fp32) ----------------
__global__ __launch_bounds__(256)
void k_scores(const float* __restrict__ x, const float* __restrict__ Qb,
              const int* __restrict__ idx_i, float* __restrict__ scores)
{
    int b = blockIdx.z;
    int k0 = blockIdx.y * 64;
    int p0 = blockIdx.x * 64;
    const float* A  = Qb + (size_t)idx_i[b] * Kk * Dd + (size_t)k0 * Dd;
    const float* Bm = x + (size_t)b * Nn * Dd + (size_t)Rr * Dd + (size_t)p0 * Dd;
    __shared__ float As[16][68] __attribute__((aligned(16)));
    __shared__ float Bs[16][68] __attribute__((aligned(16)));
    int t = threadIdx.x, tx = t & 15, ty = t >> 4;
    int lrow = t >> 2, lc4 = (t & 3) * 4;
    float acc[4][4] = {};
    for (int d0 = 0; d0 < Dd; d0 += 16) {
        float4 av = *(const float4*)(A  + (size_t)lrow * Dd + d0 + lc4);
        float4 bv = *(const float4*)(Bm + (size_t)lrow * Dd + d0 + lc4);
        As[lc4+0][lrow] = av.x; As[lc4+1][lrow] = av.y;
        As[lc4+2][lrow] = av.z; As[lc4+3][lrow] = av.w;
        Bs[lc4+0][lrow] = bv.x; Bs[lc4+1][lrow] = bv.y;
        Bs[lc4+2][lrow] = bv.z; Bs[lc4+3][lrow] = bv.w;
        __syncthreads();
        #pragma unroll
        for (int kk = 0; kk < 16; kk++) {
            float4 a  = *(const float4*)&As[kk][ty * 4];
            float4 b4 = *(const float4*)&Bs[kk][tx * 4];
            FMA16(acc, a, b4);
        }
        __syncthreads();
    }
    float* C = scores + ((size_t)b * Kk + k0) * Pp + p0;
    #pragma unroll
    for (int i = 0; i < 4; i++) {
        float4 v = make_float4(acc[i][0], acc[i][1], acc[i][2], acc[i][3]);
        *(float4*)(C + (size_t)(ty * 4 + i) * Pp + tx * 4) = v;
    }
}

// ---------------- K3: softmax rows of scores ----------------
__global__ __launch_bounds__(256)
void k_softmax(float* __restrict__ scores)
{
    size_t row = blockIdx.x;
    float* s = scores + row * Pp;
    int t = threadIdx.x;
    float v[4];
    float mx = -3.4e38f;
    #pragma unroll
    for (int j = 0; j < 4; j++) { v[j] = s[t + j * 256]; mx = fmaxf(mx, v[j]); }
    for (int o = 32; o > 0; o >>= 1) mx = fmaxf(mx, __shfl_down(mx, o));
    __shared__ float wred[4];
    int lane = t & 63, wid = t >> 6;
    if (lane == 0) wred[wid] = mx;
    __syncthreads();
    mx = fmaxf(fmaxf(wred[0], wred[1]), fmaxf(wred[2], wred[3]));
    float sum = 0.f;
    #pragma unroll
    for (int j = 0; j < 4; j++) { v[j] = __expf(v[j] - mx); sum += v[j]; }
    for (int o = 32; o > 0; o >>= 1) sum += __shfl_down(sum, o);
    __syncthreads();
    if (lane == 0) wred[wid] = sum;
    __syncthreads();
    sum = wred[0] + wred[1] + wred[2] + wred[3];
    float inv = 1.f / sum;
    #pragma unroll
    for (int j = 0; j < 4; j++) s[t + j * 256] = v[j] * inv;
}

// ---------------- K4: ctx_p = attn @ xp  (NN GEMM, fp32) ----------------
__global__ __launch_bounds__(256)
void k_ctxp(const float* __restrict__ scores, const float* __restrict__ x,
            float* __restrict__ ctx)
{
    int b = blockIdx.z;
    int k0 = blockIdx.y * 64;
    int c0 = blockIdx.x * 64;
    const float* A  = scores + ((size_t)b * Kk + k0) * Pp;
    const float* Bm = x + (size_t)b * Nn * Dd + (size_t)Rr * Dd;
    __shared__ float As[16][68] __attribute__((aligned(16)));
    __shared__ float Bs[16][68] __attribute__((aligned(16)));
    int t = threadIdx.x, tx = t & 15, ty = t >> 4;
    int arow = t >> 2, ac4 = (t & 3) * 4;
    int brow = t >> 4, bc4 = (t & 15) * 4;
    float acc[4][4] = {};
    for (int p0 = 0; p0 < Pp; p0 += 16) {
        float4 av = *(const float4*)(A + (size_t)arow * Pp + p0 + ac4);
        As[ac4+0][arow] = av.x; As[ac4+1][arow] = av.y;
        As[ac4+2][arow] = av.z; As[ac4+3][arow] = av.w;
        float4 bv = *(const float4*)(Bm + (size_t)(p0 + brow) * Dd + c0 + bc4);
        Bs[brow][bc4+0] = bv.x; Bs[brow][bc4+1] = bv.y;
        Bs[brow][bc4+2] = bv.z; Bs[brow][bc4+3] = bv.w;
        __syncthreads();
        #pragma unroll
        for (int kk = 0; kk < 16; kk++) {
            float4 a  = *(const float4*)&As[kk][ty * 4];
            float4 b4 = *(const float4*)&Bs[kk][tx * 4];
            FMA16(acc, a, b4);
        }
        __syncthreads();
    }
    float* C = ctx + ((size_t)b * CTX + Rr + k0) * Dd + c0;
    #pragma unroll
    for (int i = 0; i < 4; i++) {
        float4 v = make_float4(acc[i][0], acc[i][1], acc[i][2], acc[i][3]);
        *(float4*)(C + (size_t)(ty * 4 + i) * Dd + tx * 4) = v;
    }
}

// ---------------- K4b: copy xreg rows into ctx ----------------
__global__ __launch_bounds__(256)
void k_xreg(const float* __restrict__ x, float* __restrict__ ctx)
{
    int b = blockIdx.x, t = threadIdx.x;
    const float* src = x + (size_t)b * Nn * Dd;
    float* dst = ctx + (size_t)b * CTX * Dd;
    for (int i = t; i < Rr * Dd; i += 256) dst[i] = src[i];
}

// ---------------- K5: kv = ctx @ Wctx + bctx  (NN GEMM, fp32 in, bf16 out) ----------------
__global__ __launch_bounds__(256)
void k_kv(const float* __restrict__ ctx, const float* __restrict__ Wctx,
          const float* __restrict__ bctx, u16* __restrict__ kvb)
{
    int b = blockIdx.z;
    int m0 = blockIdx.y * 64;
    int c0 = blockIdx.x * 64;
    const float* A = ctx + (size_t)b * CTX * Dd;
    __shared__ float As[16][68] __attribute__((aligned(16)));
    __shared__ float Bs[16][68] __attribute__((aligned(16)));
    int t = threadIdx.x, tx = t & 15, ty = t >> 4;
    int arow = t >> 2, ac4 = (t & 3) * 4;
    int brow = t >> 4, bc4 = (t & 15) * 4;
    int am = m0 + arow;
    float acc[4][4] = {};
    for (int d0 = 0; d0 < Dd; d0 += 16) {
        float4 av = (am < CTX) ? *(const float4*)(A + (size_t)am * Dd + d0 + ac4)
                               : make_float4(0.f, 0.f, 0.f, 0.f);
        As[ac4+0][arow] = av.x; As[ac4+1][arow] = av.y;
        As[ac4+2][arow] = av.z; As[ac4+3][arow] = av.w;
        float4 bv = *(const float4*)(Wctx + (size_t)(d0 + brow) * TWO_D + c0 + bc4);
        Bs[brow][bc4+0] = bv.x; Bs[brow][bc4+1] = bv.y;
        Bs[brow][bc4+2] = bv.z; Bs[brow][bc4+3] = bv.w;
        __syncthreads();
        #pragma unroll
        for (int kk = 0; kk < 16; kk++) {
            float4 a  = *(const float4*)&As[kk][ty * 4];
            float4 b4 = *(const float4*)&Bs[kk][tx * 4];
            FMA16(acc, a, b4);
        }
        __syncthreads();
    }
    float bias[4];
    #pragma unroll
    for (int j = 0; j < 4; j++) bias[j] = bctx[c0 + tx * 4 + j];
    #pragma unroll
    for (int i = 0; i < 4; i++) {
        int m = m0 + ty * 4 + i;
        if (m < CTX) {
            ushort4 o;
            o.x = f2bs(acc[i][0] + bias[0]); o.y = f2bs(acc[i][1] + bias[1]);
            o.z = f2bs(acc[i][2] + bias[2]); o.w = f2bs(acc[i][3] + bias[3]);
            *(ushort4*)(kvb + ((size_t)b * CTX + m) * TWO_D + c0 + tx * 4) = o;
        }
    }
}

// ---------------- K6a: q = (x @ Wq) * 0.125, bf16, written into the y buffer ----------------
// MFMA bf16 GEMM: rows = B*N = 65856 (exactly 1029 tiles of 64), cols = 768, K = 768.
__global__ __launch_bounds__(256)
void k_q(const float* __restrict__ x, const float* __restrict__ Wq,
         u16* __restrict__ q)
{
    int c0 = blockIdx.x * 64;
    int r0 = blockIdx.y * 64;
    __shared__ u16 xs [64][40] __attribute__((aligned(16)));  // row stride 80B: 2-way bank alias max
    __shared__ u16 wqs[64][40] __attribute__((aligned(16)));  // wqs[n][k] = Wq[k][c0+n]
    int t = threadIdx.x;
    int lane = t & 63, wv = t >> 6;
    int lr = lane & 15, lg = lane >> 4;
    int sr = t >> 2, sc = (t & 3) * 8;   // xs stage: 64 rows x 32 k
    int wr = t >> 3, wc = (t & 7) * 8;   // wqs stage: 32 k-rows x 64 n
    f32x4 acc[4] = {};
    for (int d0 = 0; d0 < Dd; d0 += 32) {
        float4 xa = *(const float4*)(x + (size_t)(r0 + sr) * Dd + d0 + sc);
        float4 xb = *(const float4*)(x + (size_t)(r0 + sr) * Dd + d0 + sc + 4);
        float4 wa = *(const float4*)(Wq + (size_t)(d0 + wr) * Dd + c0 + wc);
        float4 wb = *(const float4*)(Wq + (size_t)(d0 + wr) * Dd + c0 + wc + 4);
        __syncthreads();  // previous-iter LDS reads done before overwrite
        ushort4 x0; x0.x = f2bs(xa.x); x0.y = f2bs(xa.y); x0.z = f2bs(xa.z); x0.w = f2bs(xa.w);
        ushort4 x1; x1.x = f2bs(xb.x); x1.y = f2bs(xb.y); x1.z = f2bs(xb.z); x1.w = f2bs(xb.w);
        *(ushort4*)&xs[sr][sc]     = x0;
        *(ushort4*)&xs[sr][sc + 4] = x1;
        wqs[wc+0][wr] = f2bs(wa.x); wqs[wc+1][wr] = f2bs(wa.y);
        wqs[wc+2][wr] = f2bs(wa.z); wqs[wc+3][wr] = f2bs(wa.w);
        wqs[wc+4][wr] = f2bs(wb.x); wqs[wc+5][wr] = f2bs(wb.y);
        wqs[wc+6][wr] = f2bs(wb.z); wqs[wc+7][wr] = f2bs(wb.w);
        __syncthreads();
        bf16x8 a = *(const bf16x8*)&xs[wv * 16 + lr][lg * 8];
        #pragma unroll
        for (int nt = 0; nt < 4; nt++) {
            bf16x8 bfr = *(const bf16x8*)&wqs[nt * 16 + lr][lg * 8];
            acc[nt] = __builtin_amdgcn_mfma_f32_16x16x32_bf16(a, bfr, acc[nt], 0, 0, 0);
        }
    }
    // C/D layout: col = lane&15, row = (lane>>4)*4 + reg  [verified gfx950 mapping]
    #pragma unroll
    for (int nt = 0; nt < 4; nt++)
        #pragma unroll
        for (int r = 0; r < 4; r++)
            q[(size_t)(r0 + wv * 16 + lg * 4 + r) * Dd + c0 + nt * 16 + lr] =
                f2bs(acc[nt][r] * 0.125f);
}

// ---------------- K6b: attention via MFMA: logits -> softmax -> PV, overwrites q with y ----------------
// Block: one (b, h), 64 q-rows (4 waves x 16). CTX=133 padded to 144 (QK tiles) / 160 (PV k-dim).
__global__ __launch_bounds__(256)
void k_attn(const u16* __restrict__ kvb, u16* __restrict__ qy)
{
    int n0 = blockIdx.x * 64;
    int h  = blockIdx.y;
    int b  = blockIdx.z;
    int t = threadIdx.x;
    int lane = t & 63, wv = t >> 6;
    int lr = lane & 15, lg = lane >> 4;

    __shared__ u16 ks [144][72]      __attribute__((aligned(16)));  // K rows, stride 144B
    __shared__ u16 vst[64][168]      __attribute__((aligned(16)));  // V^T: [dh][p], stride 336B
    __shared__ u16 ps [4][16][168]   __attribute__((aligned(16)));  // per-wave P (bf16)

    // ---- load this wave's q fragments (must precede the y overwrite; same buffer) ----
    int qn = n0 + wv * 16 + lr;
    size_t qrow = (size_t)b * Nn + (qn < Nn ? qn : Nn - 1);
    bf16x8 aq0 = *(const bf16x8*)(qy + qrow * Dd + h * DH + lg * 8);
    bf16x8 aq1 = *(const bf16x8*)(qy + qrow * Dd + h * DH + 32 + lg * 8);

    // ---- stage K (row-major) and V (transposed) into LDS; zero the pads ----
    const u16* kvrow = kvb + (size_t)b * CTX * TWO_D + h * DH;
    for (int e4 = t * 4; e4 < CTX * DH; e4 += 1024) {
        int m = e4 >> 6, dd = e4 & 63;
        *(ushort4*)&ks[m][dd] = *(const ushort4*)(kvrow + (size_t)m * TWO_D + dd);
        ushort4 vv = *(const ushort4*)(kvrow + (size_t)m * TWO_D + Dd + dd);
        vst[dd + 0][m] = vv.x; vst[dd + 1][m] = vv.y;
        vst[dd + 2][m] = vv.z; vst[dd + 3][m] = vv.w;
    }
    for (int i = t; i < 11 * 64; i += 256) ks[133 + (i >> 6)][i & 63] = 0;    // K rows 133..143
    for (int i = t; i < 64 * 27; i += 256) vst[i / 27][133 + i % 27] = 0;     // V^T cols 133..159
    for (int i = t; i < 64 * 16; i += 256) {                                  // P cols 144..159
        int rr = i >> 4;
        ps[rr >> 4][rr & 15][144 + (i & 15)] = 0;
    }
    __syncthreads();

    // ---- QK^T: 9 n-tiles of 16 k-rows; k-dim = 64 = 2 mfma ----
    f32x4 stile[9];
    #pragma unroll
    for (int tn = 0; tn < 9; tn++) {
        bf16x8 bk0 = *(const bf16x8*)&ks[tn * 16 + lr][lg * 8];
        bf16x8 bk1 = *(const bf16x8*)&ks[tn * 16 + lr][32 + lg * 8];
        f32x4 a = {0.f, 0.f, 0.f, 0.f};
        a = __builtin_amdgcn_mfma_f32_16x16x32_bf16(aq0, bk0, a, 0, 0, 0);
        a = __builtin_amdgcn_mfma_f32_16x16x32_bf16(aq1, bk1, a, 0, 0, 0);
        stile[tn] = a;
    }

    // ---- softmax per output row; row m's 144 logits live in the 16 lanes of this lg-group ----
    #pragma unroll
    for (int r = 0; r < 4; r++) {
        float m_ = -3.4e38f;
        #pragma unroll
        for (int tn = 0; tn < 9; tn++) {
            float v = stile[tn][r];
            if (tn == 8 && lr >= 5) v = -3.4e38f;   // n = 128 + lr >= 133 -> masked
            m_ = fmaxf(m_, v);
        }
        m_ = fmaxf(m_, __shfl_xor(m_, 1));
        m_ = fmaxf(m_, __shfl_xor(m_, 2));
        m_ = fmaxf(m_, __shfl_xor(m_, 4));
        m_ = fmaxf(m_, __shfl_xor(m_, 8));
        float pv[9];
        float s_ = 0.f;
        #pragma unroll
        for (int tn = 0; tn < 9; tn++) {
            float v = stile[tn][r];
            v = (tn == 8 && lr >= 5) ? 0.f : __expf(v - m_);
            pv[tn] = v; s_ += v;
        }
        s_ += __shfl_xor(s_, 1);
        s_ += __shfl_xor(s_, 2);
        s_ += __shfl_xor(s_, 4);
        s_ += __shfl_xor(s_, 8);
        float inv = 1.f / s_;
        #pragma unroll
        for (int tn = 0; tn < 9; tn++)
            ps[wv][lg * 4 + r][tn * 16 + lr] = f2bs(pv[tn] * inv);
    }
    __syncthreads();   // ps (incl. zero pads) visible before PV fragment reads

    // ---- PV: y[16 x 64] = P[16 x 160] @ V[160 x 64] (V^T rows as B-fragments) ----
    f32x4 yacc[4] = {};
    #pragma unroll
    for (int kk = 0; kk < 5; kk++) {
        bf16x8 ap = *(const bf16x8*)&ps[wv][lr][kk * 32 + lg * 8];
        #pragma unroll
        for (int td = 0; td < 4; td++) {
            bf16x8 bv = *(const bf16x8*)&vst[td * 16 + lr][kk * 32 + lg * 8];
            yacc[td] = __builtin_amdgcn_mfma_f32_16x16x32_bf16(ap, bv, yacc[td], 0, 0, 0);
        }
    }

    // ---- store y (overwrites this block's q region; q already consumed) ----
    #pragma unroll
    for (int td = 0; td < 4; td++)
        #pragma unroll
        for (int r = 0; r < 4; r++) {
            int gn = n0 + wv * 16 + lg * 4 + r;
            if (gn < Nn)
                qy[((size_t)b * Nn + gn) * Dd + h * DH + td * 16 + lr] = f2bs(yacc[td][r]);
        }
}

// ---------------- K7: out = y @ Wout + bout  (y bf16, rest fp32) ----------------
__global__ __launch_bounds__(256)
void k_out(const u16* __restrict__ y, const float* __restrict__ Wout,
           const float* __restrict__ bout, float* __restrict__ outp)
{
    int r0 = blockIdx.y * 64;
    int c0 = blockIdx.x * 64;
    __shared__ float As[16][68] __attribute__((aligned(16)));
    __shared__ float Bs[16][68] __attribute__((aligned(16)));
    int t = threadIdx.x, tx = t & 15, ty = t >> 4;
    int arow = t >> 2, ac4 = (t & 3) * 4;
    int brow = t >> 4, bc4 = (t & 15) * 4;
    float acc[4][4] = {};
    const u16* Arow = y + (size_t)(r0 + arow) * Dd;
    for (int d0 = 0; d0 < Dd; d0 += 16) {
        ushort4 av = *(const ushort4*)(Arow + d0 + ac4);
        As[ac4+0][arow] = bs2f(av.x); As[ac4+1][arow] = bs2f(av.y);
        As[ac4+2][arow] = bs2f(av.z); As[ac4+3][arow] = bs2f(av.w);
        float4 bv = *(const float4*)(Wout + (size_t)(d0 + brow) * Dd + c0 + bc4);
        Bs[brow][bc4+0] = bv.x; Bs[brow][bc4+1] = bv.y;
        Bs[brow][bc4+2] = bv.z; Bs[brow][bc4+3] = bv.w;
        __syncthreads();
        #pragma unroll
        for (int kk = 0; kk < 16; kk++) {
            float4 a  = *(const float4*)&As[kk][ty * 4];
            float4 b4 = *(const float4*)&Bs[kk][tx * 4];
            FMA16(acc, a, b4);
        }
        __syncthreads();
    }
    float bias[4];
    #pragma unroll
    for (int j = 0; j < 4; j++) bias[j] = bout[c0 + tx * 4 + j];
    #pragma unroll
    for (int i = 0; i < 4; i++) {
        float4 v = make_float4(acc[i][0] + bias[0], acc[i][1] + bias[1],
                               acc[i][2] + bias[2], acc[i][3] + bias[3]);
        *(float4*)(outp + (size_t)(r0 + ty * 4 + i) * Dd + c0 + tx * 4) = v;
    }
}

extern "C" void kernel_launch(void* const* d_in, const int* in_sizes, int n_in,
                              void* d_out, int out_size, void* d_ws, size_t ws_size,
                              hipStream_t stream)
{
    const float* x    = (const float*)d_in[0];
    const float* Qb   = (const float*)d_in[1];
    const float* Wq   = (const float*)d_in[2];
    const float* Wctx = (const float*)d_in[3];
    const float* bctx = (const float*)d_in[4];
    const float* Wout = (const float*)d_in[5];
    const float* bout = (const float*)d_in[6];
    const float* cent = (const float*)d_in[7];

    float* out     = (float*)d_out;
    float* out_cls = out + (size_t)Bc * Nn * Dd;
    float* out_idx = out_cls + (size_t)Bc * Dd;

    // ws layout: [idx(1KB)] [scores fp32 33.5MB / kvb bf16 26.1MB (reused)] [ctx fp32 26.2MB] [q/y bf16 101.2MB (aliased)]
    const size_t SC_B  = (size_t)Bc * Kk * Pp * 4;   // 33,554,432
    const size_t CTX_B = (size_t)Bc * CTX * Dd * 4;  // 26,148,864
    const size_t Y_B   = (size_t)Bc * Nn * Dd * 2;   // 101,154,816
    const size_t NEED  = 1024 + SC_B + CTX_B + Y_B;  // 160,859,136
    if (ws_size < NEED) return;  // fail loudly (zero outputs) rather than corrupt memory

    char* w = (char*)d_ws;
    int*   idx_i  = (int*)w;
    float* scores = (float*)(w + 1024);
    u16*   kvb    = (u16*)(w + 1024);               // reuses scores region after K4
    float* ctx    = (float*)(w + 1024 + SC_B);
    u16*   qy     = (u16*)(w + 1024 + SC_B + CTX_B); // q written by k_q, overwritten with y by k_attn

    k_cls    <<<Bc, 256, 0, stream>>>(x, cent, out_cls, out_idx, idx_i);
    k_q      <<<dim3(12, 1029), 256, 0, stream>>>(x, Wq, qy);
    k_scores <<<dim3(16, 2, Bc), 256, 0, stream>>>(x, Qb, idx_i, scores);
    k_softmax<<<Bc * Kk, 256, 0, stream>>>(scores);
    k_ctxp   <<<dim3(12, 2, Bc), 256, 0, stream>>>(scores, x, ctx);
    k_xreg   <<<Bc, 256, 0, stream>>>(x, ctx);
    k_kv     <<<dim3(24, 3, Bc), 256, 0, stream>>>(ctx, Wctx, bctx, kvb);
    k_attn   <<<dim3(17, Hh, Bc), 256, 0, stream>>>(kvb, qy);
    k_out    <<<dim3(12, 1029), 256, 0, stream>>>(qy, Wout, bout, out);
}

// Round 2
// 1774.969 us; speedup vs baseline: 3.9389x; 1.3732x over previous
//
#include <hip/hip_runtime.h>
#include <hip/hip_bf16.h>

#define Bc 64
#define Nn 1029
#define Dd 768
#define Hh 12
#define DH 64
#define Kk 128
#define Rr 5
#define Mm 4
#define Pp 1024
#define CTX 133
#define TWO_D 1536

typedef unsigned short u16;
typedef __attribute__((ext_vector_type(8))) short bf16x8;   // 8 bf16 = 4 VGPRs
typedef __attribute__((ext_vector_type(4))) float f32x4;

__device__ __forceinline__ float bs2f(u16 u){
    union { unsigned int i; float f; } c; c.i = ((unsigned)u) << 16; return c.f;
}
__device__ __forceinline__ u16 f2bs(float f){
    unsigned int u = __float_as_uint(f);
    unsigned int r = (u + 0x7fffu + ((u >> 16) & 1u)) >> 16;  // RNE
    return (u16)r;
}

#define FMA16(acc, a, b4) do { \
    acc[0][0] += a.x*b4.x; acc[0][1] += a.x*b4.y; acc[0][2] += a.x*b4.z; acc[0][3] += a.x*b4.w; \
    acc[1][0] += a.y*b4.x; acc[1][1] += a.y*b4.y; acc[1][2] += a.y*b4.z; acc[1][3] += a.y*b4.w; \
    acc[2][0] += a.z*b4.x; acc[2][1] += a.z*b4.y; acc[2][2] += a.z*b4.z; acc[2][3] += a.z*b4.w; \
    acc[3][0] += a.w*b4.x; acc[3][1] += a.w*b4.y; acc[3][2] += a.w*b4.z; acc[3][3] += a.w*b4.w; \
} while(0)

// ---------------- K1: cls_n + argmax idx ----------------
__global__ __launch_bounds__(256)
void k_cls(const float* __restrict__ x, const float* __restrict__ cent,
           float* __restrict__ out_cls, float* __restrict__ out_idx,
           int* __restrict__ idx_i)
{
    int b = blockIdx.x, t = threadIdx.x;
    const float* xr = x + (size_t)b * Nn * Dd;
    __shared__ float sx[Dd];
    __shared__ float wred[4];
    float ss = 0.f;
    for (int i = t; i < Dd; i += 256) { float v = xr[i]; sx[i] = v; ss += v * v; }
    for (int o = 32; o > 0; o >>= 1) ss += __shfl_down(ss, o);
    int lane = t & 63, wid = t >> 6;
    if (lane == 0) wred[wid] = ss;
    __syncthreads();
    float tot = wred[0] + wred[1] + wred[2] + wred[3];
    float inv = 1.f / fmaxf(sqrtf(tot), 1e-12f);
    __syncthreads();
    for (int i = t; i < Dd; i += 256) { float v = sx[i] * inv; sx[i] = v; out_cls[(size_t)b * Dd + i] = v; }
    __syncthreads();
    float sm[Mm];
    for (int m = 0; m < Mm; m++) {
        float s = 0.f;
        for (int i = t; i < Dd; i += 256) s += sx[i] * cent[m * Dd + i];
        for (int o = 32; o > 0; o >>= 1) s += __shfl_down(s, o);
        __syncthreads();
        if (lane == 0) wred[wid] = s;
        __syncthreads();
        sm[m] = wred[0] + wred[1] + wred[2] + wred[3];
    }
    if (t == 0) {
        int best = 0; float bv = sm[0];
        for (int m = 1; m < Mm; m++) if (sm[m] > bv) { bv = sm[m]; best = m; }
        idx_i[b] = best;
        out_idx[b] = (float)best;
    }
}

// ---------------- K2: scores = Q_banks[idx] @ xp^T  (NT GEMM, fp32) ----------------
__global__ __launch_bounds__(256)
void k_scores(const float* __restrict__ x, const float* __restrict__ Qb,
              const int* __restrict__ idx_i, float* __restrict__ scores)
{
    int b = blockIdx.z;
    int k0 = blockIdx.y * 64;
    int p0 = blockIdx.x * 64;
    const float* A  = Qb + (size_t)idx_i[b] * Kk * Dd + (size_t)k0 * Dd;
    const float* Bm = x + (size_t)b * Nn * Dd + (size_t)Rr * Dd + (size_t)p0 * Dd;
    __shared__ float As[16][68] __attribute__((aligned(16)));
    __shared__ float Bs[16][68] __attribute__((aligned(16)));
    int t = threadIdx.x, tx = t & 15, ty = t >> 4;
    int lrow = t >> 2, lc4 = (t & 3) * 4;
    float acc[4][4] = {};
    for (int d0 = 0; d0 < Dd; d0 += 16) {
        float4 av = *(const float4*)(A  + (size_t)lrow * Dd + d0 + lc4);
        float4 bv = *(const float4*)(Bm + (size_t)lrow * Dd + d0 + lc4);
        As[lc4+0][lrow] = av.x; As[lc4+1][lrow] = av.y;
        As[lc4+2][lrow] = av.z; As[lc4+3][lrow] = av.w;
        Bs[lc4+0][lrow] = bv.x; Bs[lc4+1][lrow] = bv.y;
        Bs[lc4+2][lrow] = bv.z; Bs[lc4+3][lrow] = bv.w;
        __syncthreads();
        #pragma unroll
        for (int kk = 0; kk < 16; kk++) {
            float4 a  = *(const float4*)&As[kk][ty * 4];
            float4 b4 = *(const float4*)&Bs[kk][tx * 4];
            FMA16(acc, a, b4);
        }
        __syncthreads();
    }
    float* C = scores + ((size_t)b * Kk + k0) * Pp + p0;
    #pragma unroll
    for (int i = 0; i < 4; i++) {
        float4 v = make_float4(acc[i][0], acc[i][1], acc[i][2], acc[i][3]);
        *(float4*)(C + (size_t)(ty * 4 + i) * Pp + tx * 4) = v;
    }
}

// ---------------- K3: softmax rows of scores ----------------
__global__ __launch_bounds__(256)
void k_softmax(float* __restrict__ scores)
{
    size_t row = blockIdx.x;
    float* s = scores + row * Pp;
    int t = threadIdx.x;
    float v[4];
    float mx = -3.4e38f;
    #pragma unroll
    for (int j = 0; j < 4; j++) { v[j] = s[t + j * 256]; mx = fmaxf(mx, v[j]); }
    for (int o = 32; o > 0; o >>= 1) mx = fmaxf(mx, __shfl_down(mx, o));
    __shared__ float wred[4];
    int lane = t & 63, wid = t >> 6;
    if (lane == 0) wred[wid] = mx;
    __syncthreads();
    mx = fmaxf(fmaxf(wred[0], wred[1]), fmaxf(wred[2], wred[3]));
    float sum = 0.f;
    #pragma unroll
    for (int j = 0; j < 4; j++) { v[j] = __expf(v[j] - mx); sum += v[j]; }
    for (int o = 32; o > 0; o >>= 1) sum += __shfl_down(sum, o);
    __syncthreads();
    if (lane == 0) wred[wid] = sum;
    __syncthreads();
    sum = wred[0] + wred[1] + wred[2] + wred[3];
    float inv = 1.f / sum;
    #pragma unroll
    for (int j = 0; j < 4; j++) s[t + j * 256] = v[j] * inv;
}

// ---------------- K4: ctx_p = attn @ xp  (NN GEMM, fp32) ----------------
__global__ __launch_bounds__(256)
void k_ctxp(const float* __restrict__ scores, const float* __restrict__ x,
            float* __restrict__ ctx)
{
    int b = blockIdx.z;
    int k0 = blockIdx.y * 64;
    int c0 = blockIdx.x * 64;
    const float* A  = scores + ((size_t)b * Kk + k0) * Pp;
    const float* Bm = x + (size_t)b * Nn * Dd + (size_t)Rr * Dd;
    __shared__ float As[16][68] __attribute__((aligned(16)));
    __shared__ float Bs[16][68] __attribute__((aligned(16)));
    int t = threadIdx.x, tx = t & 15, ty = t >> 4;
    int arow = t >> 2, ac4 = (t & 3) * 4;
    int brow = t >> 4, bc4 = (t & 15) * 4;
    float acc[4][4] = {};
    for (int p0 = 0; p0 < Pp; p0 += 16) {
        float4 av = *(const float4*)(A + (size_t)arow * Pp + p0 + ac4);
        As[ac4+0][arow] = av.x; As[ac4+1][arow] = av.y;
        As[ac4+2][arow] = av.z; As[ac4+3][arow] = av.w;
        float4 bv = *(const float4*)(Bm + (size_t)(p0 + brow) * Dd + c0 + bc4);
        Bs[brow][bc4+0] = bv.x; Bs[brow][bc4+1] = bv.y;
        Bs[brow][bc4+2] = bv.z; Bs[brow][bc4+3] = bv.w;
        __syncthreads();
        #pragma unroll
        for (int kk = 0; kk < 16; kk++) {
            float4 a  = *(const float4*)&As[kk][ty * 4];
            float4 b4 = *(const float4*)&Bs[kk][tx * 4];
            FMA16(acc, a, b4);
        }
        __syncthreads();
    }
    float* C = ctx + ((size_t)b * CTX + Rr + k0) * Dd + c0;
    #pragma unroll
    for (int i = 0; i < 4; i++) {
        float4 v = make_float4(acc[i][0], acc[i][1], acc[i][2], acc[i][3]);
        *(float4*)(C + (size_t)(ty * 4 + i) * Dd + tx * 4) = v;
    }
}

// ---------------- K4b: copy xreg rows into ctx ----------------
__global__ __launch_bounds__(256)
void k_xreg(const float* __restrict__ x, float* __restrict__ ctx)
{
    int b = blockIdx.x, t = threadIdx.x;
    const float* src = x + (size_t)b * Nn * Dd;
    float* dst = ctx + (size_t)b * CTX * Dd;
    for (int i = t; i < Rr * Dd; i += 256) dst[i] = src[i];
}

// ---------------- K5: kv = ctx @ Wctx + bctx  (bf16 MFMA, fp32 in via cvt, bf16 out) ----------------
__global__ __launch_bounds__(256)
void k_kv(const float* __restrict__ ctx, const float* __restrict__ Wctx,
          const float* __restrict__ bctx, u16* __restrict__ kvb)
{
    int c0 = blockIdx.x * 64;   // 24 tiles over TWO_D=1536
    int m0 = blockIdx.y * 64;   // 3 tiles over CTX=133 (tail clamped/masked)
    int b  = blockIdx.z;
    const float* A = ctx + (size_t)b * CTX * Dd;
    __shared__ u16 as [64][40] __attribute__((aligned(16)));
    __shared__ u16 ws [64][40] __attribute__((aligned(16)));  // ws[n][k] = Wctx[k][c0+n]
    int t = threadIdx.x;
    int lane = t & 63, wv = t >> 6;
    int lr = lane & 15, lg = lane >> 4;
    int sr = t >> 2, sc = (t & 3) * 8;   // as stage: 64 rows x 32 k
    int wr = t >> 3, wc = (t & 7) * 8;   // ws stage: 32 k-rows x 64 n
    int am = m0 + sr; if (am >= CTX) am = CTX - 1;   // clamp tail rows (stores masked)
    f32x4 acc[4] = {};
    for (int d0 = 0; d0 < Dd; d0 += 32) {
        float4 xa = *(const float4*)(A + (size_t)am * Dd + d0 + sc);
        float4 xb = *(const float4*)(A + (size_t)am * Dd + d0 + sc + 4);
        float4 wa = *(const float4*)(Wctx + (size_t)(d0 + wr) * TWO_D + c0 + wc);
        float4 wb = *(const float4*)(Wctx + (size_t)(d0 + wr) * TWO_D + c0 + wc + 4);
        __syncthreads();  // previous-iter LDS reads done before overwrite
        ushort4 x0; x0.x = f2bs(xa.x); x0.y = f2bs(xa.y); x0.z = f2bs(xa.z); x0.w = f2bs(xa.w);
        ushort4 x1; x1.x = f2bs(xb.x); x1.y = f2bs(xb.y); x1.z = f2bs(xb.z); x1.w = f2bs(xb.w);
        *(ushort4*)&as[sr][sc]     = x0;
        *(ushort4*)&as[sr][sc + 4] = x1;
        ws[wc+0][wr] = f2bs(wa.x); ws[wc+1][wr] = f2bs(wa.y);
        ws[wc+2][wr] = f2bs(wa.z); ws[wc+3][wr] = f2bs(wa.w);
        ws[wc+4][wr] = f2bs(wb.x); ws[wc+5][wr] = f2bs(wb.y);
        ws[wc+6][wr] = f2bs(wb.z); ws[wc+7][wr] = f2bs(wb.w);
        __syncthreads();
        bf16x8 a = *(const bf16x8*)&as[wv * 16 + lr][lg * 8];
        #pragma unroll
        for (int nt = 0; nt < 4; nt++) {
            bf16x8 bfr = *(const bf16x8*)&ws[nt * 16 + lr][lg * 8];
            acc[nt] = __builtin_amdgcn_mfma_f32_16x16x32_bf16(a, bfr, acc[nt], 0, 0, 0);
        }
    }
    // C/D layout: col = lane&15, row = (lane>>4)*4 + reg
    #pragma unroll
    for (int nt = 0; nt < 4; nt++) {
        float bias = bctx[c0 + nt * 16 + lr];
        #pragma unroll
        for (int r = 0; r < 4; r++) {
            int m = m0 + wv * 16 + lg * 4 + r;
            if (m < CTX)
                kvb[((size_t)b * CTX + m) * TWO_D + c0 + nt * 16 + lr] =
                    f2bs(acc[nt][r] + bias);
        }
    }
}

// ---------------- K6a: q = (x @ Wq) * 0.125, bf16, written into the y buffer ----------------
// MFMA bf16 GEMM: rows = B*N = 65856 (exactly 1029 tiles of 64), cols = 768, K = 768.
__global__ __launch_bounds__(256)
void k_q(const float* __restrict__ x, const float* __restrict__ Wq,
         u16* __restrict__ q)
{
    int c0 = blockIdx.x * 64;
    int r0 = blockIdx.y * 64;
    __shared__ u16 xs [64][40] __attribute__((aligned(16)));  // row stride 80B: 2-way bank alias max
    __shared__ u16 wqs[64][40] __attribute__((aligned(16)));  // wqs[n][k] = Wq[k][c0+n]
    int t = threadIdx.x;
    int lane = t & 63, wv = t >> 6;
    int lr = lane & 15, lg = lane >> 4;
    int sr = t >> 2, sc = (t & 3) * 8;   // xs stage: 64 rows x 32 k
    int wr = t >> 3, wc = (t & 7) * 8;   // wqs stage: 32 k-rows x 64 n
    f32x4 acc[4] = {};
    for (int d0 = 0; d0 < Dd; d0 += 32) {
        float4 xa = *(const float4*)(x + (size_t)(r0 + sr) * Dd + d0 + sc);
        float4 xb = *(const float4*)(x + (size_t)(r0 + sr) * Dd + d0 + sc + 4);
        float4 wa = *(const float4*)(Wq + (size_t)(d0 + wr) * Dd + c0 + wc);
        float4 wb = *(const float4*)(Wq + (size_t)(d0 + wr) * Dd + c0 + wc + 4);
        __syncthreads();  // previous-iter LDS reads done before overwrite
        ushort4 x0; x0.x = f2bs(xa.x); x0.y = f2bs(xa.y); x0.z = f2bs(xa.z); x0.w = f2bs(xa.w);
        ushort4 x1; x1.x = f2bs(xb.x); x1.y = f2bs(xb.y); x1.z = f2bs(xb.z); x1.w = f2bs(xb.w);
        *(ushort4*)&xs[sr][sc]     = x0;
        *(ushort4*)&xs[sr][sc + 4] = x1;
        wqs[wc+0][wr] = f2bs(wa.x); wqs[wc+1][wr] = f2bs(wa.y);
        wqs[wc+2][wr] = f2bs(wa.z); wqs[wc+3][wr] = f2bs(wa.w);
        wqs[wc+4][wr] = f2bs(wb.x); wqs[wc+5][wr] = f2bs(wb.y);
        wqs[wc+6][wr] = f2bs(wb.z); wqs[wc+7][wr] = f2bs(wb.w);
        __syncthreads();
        bf16x8 a = *(const bf16x8*)&xs[wv * 16 + lr][lg * 8];
        #pragma unroll
        for (int nt = 0; nt < 4; nt++) {
            bf16x8 bfr = *(const bf16x8*)&wqs[nt * 16 + lr][lg * 8];
            acc[nt] = __builtin_amdgcn_mfma_f32_16x16x32_bf16(a, bfr, acc[nt], 0, 0, 0);
        }
    }
    // C/D layout: col = lane&15, row = (lane>>4)*4 + reg  [verified gfx950 mapping]
    #pragma unroll
    for (int nt = 0; nt < 4; nt++)
        #pragma unroll
        for (int r = 0; r < 4; r++)
            q[(size_t)(r0 + wv * 16 + lg * 4 + r) * Dd + c0 + nt * 16 + lr] =
                f2bs(acc[nt][r] * 0.125f);
}

// ---------------- K6b: attention via MFMA: logits -> softmax -> PV, overwrites q with y ----------------
// Block: one (b, h), 64 q-rows (4 waves x 16). CTX=133 padded to 144 (QK tiles) / 160 (PV k-dim).
__global__ __launch_bounds__(256)
void k_attn(const u16* __restrict__ kvb, u16* __restrict__ qy)
{
    int n0 = blockIdx.x * 64;
    int h  = blockIdx.y;
    int b  = blockIdx.z;
    int t = threadIdx.x;
    int lane = t & 63, wv = t >> 6;
    int lr = lane & 15, lg = lane >> 4;

    __shared__ u16 ks [144][72]      __attribute__((aligned(16)));  // K rows, stride 144B
    __shared__ u16 vst[64][168]      __attribute__((aligned(16)));  // V^T: [dh][p], stride 336B
    __shared__ u16 ps [4][16][168]   __attribute__((aligned(16)));  // per-wave P (bf16)

    // ---- load this wave's q fragments (must precede the y overwrite; same buffer) ----
    int qn = n0 + wv * 16 + lr;
    size_t qrow = (size_t)b * Nn + (qn < Nn ? qn : Nn - 1);
    bf16x8 aq0 = *(const bf16x8*)(qy + qrow * Dd + h * DH + lg * 8);
    bf16x8 aq1 = *(const bf16x8*)(qy + qrow * Dd + h * DH + 32 + lg * 8);

    // ---- stage K (row-major) and V (transposed) into LDS; zero the pads ----
    const u16* kvrow = kvb + (size_t)b * CTX * TWO_D + h * DH;
    for (int e4 = t * 4; e4 < CTX * DH; e4 += 1024) {
        int m = e4 >> 6, dd = e4 & 63;
        *(ushort4*)&ks[m][dd] = *(const ushort4*)(kvrow + (size_t)m * TWO_D + dd);
        ushort4 vv = *(const ushort4*)(kvrow + (size_t)m * TWO_D + Dd + dd);
        vst[dd + 0][m] = vv.x; vst[dd + 1][m] = vv.y;
        vst[dd + 2][m] = vv.z; vst[dd + 3][m] = vv.w;
    }
    for (int i = t; i < 11 * 64; i += 256) ks[133 + (i >> 6)][i & 63] = 0;    // K rows 133..143
    for (int i = t; i < 64 * 27; i += 256) vst[i / 27][133 + i % 27] = 0;     // V^T cols 133..159
    for (int i = t; i < 64 * 16; i += 256) {                                  // P cols 144..159
        int rr = i >> 4;
        ps[rr >> 4][rr & 15][144 + (i & 15)] = 0;
    }
    __syncthreads();

    // ---- QK^T: 9 n-tiles of 16 k-rows; k-dim = 64 = 2 mfma ----
    f32x4 stile[9];
    #pragma unroll
    for (int tn = 0; tn < 9; tn++) {
        bf16x8 bk0 = *(const bf16x8*)&ks[tn * 16 + lr][lg * 8];
        bf16x8 bk1 = *(const bf16x8*)&ks[tn * 16 + lr][32 + lg * 8];
        f32x4 a = {0.f, 0.f, 0.f, 0.f};
        a = __builtin_amdgcn_mfma_f32_16x16x32_bf16(aq0, bk0, a, 0, 0, 0);
        a = __builtin_amdgcn_mfma_f32_16x16x32_bf16(aq1, bk1, a, 0, 0, 0);
        stile[tn] = a;
    }

    // ---- softmax per output row; row m's 144 logits live in the 16 lanes of this lg-group ----
    #pragma unroll
    for (int r = 0; r < 4; r++) {
        float m_ = -3.4e38f;
        #pragma unroll
        for (int tn = 0; tn < 9; tn++) {
            float v = stile[tn][r];
            if (tn == 8 && lr >= 5) v = -3.4e38f;   // n = 128 + lr >= 133 -> masked
            m_ = fmaxf(m_, v);
        }
        m_ = fmaxf(m_, __shfl_xor(m_, 1));
        m_ = fmaxf(m_, __shfl_xor(m_, 2));
        m_ = fmaxf(m_, __shfl_xor(m_, 4));
        m_ = fmaxf(m_, __shfl_xor(m_, 8));
        float pv[9];
        float s_ = 0.f;
        #pragma unroll
        for (int tn = 0; tn < 9; tn++) {
            float v = stile[tn][r];
            v = (tn == 8 && lr >= 5) ? 0.f : __expf(v - m_);
            pv[tn] = v; s_ += v;
        }
        s_ += __shfl_xor(s_, 1);
        s_ += __shfl_xor(s_, 2);
        s_ += __shfl_xor(s_, 4);
        s_ += __shfl_xor(s_, 8);
        float inv = 1.f / s_;
        #pragma unroll
        for (int tn = 0; tn < 9; tn++)
            ps[wv][lg * 4 + r][tn * 16 + lr] = f2bs(pv[tn] * inv);
    }
    __syncthreads();   // ps (incl. zero pads) visible before PV fragment reads

    // ---- PV: y[16 x 64] = P[16 x 160] @ V[160 x 64] (V^T rows as B-fragments) ----
    f32x4 yacc[4] = {};
    #pragma unroll
    for (int kk = 0; kk < 5; kk++) {
        bf16x8 ap = *(const bf16x8*)&ps[wv][lr][kk * 32 + lg * 8];
        #pragma unroll
        for (int td = 0; td < 4; td++) {
            bf16x8 bv = *(const bf16x8*)&vst[td * 16 + lr][kk * 32 + lg * 8];
            yacc[td] = __builtin_amdgcn_mfma_f32_16x16x32_bf16(ap, bv, yacc[td], 0, 0, 0);
        }
    }

    // ---- store y (overwrites this block's q region; q already consumed) ----
    #pragma unroll
    for (int td = 0; td < 4; td++)
        #pragma unroll
        for (int r = 0; r < 4; r++) {
            int gn = n0 + wv * 16 + lg * 4 + r;
            if (gn < Nn)
                qy[((size_t)b * Nn + gn) * Dd + h * DH + td * 16 + lr] = f2bs(yacc[td][r]);
        }
}

// ---------------- K7: out = y @ Wout + bout  (bf16 MFMA; y already bf16, Wout cvt at stage) ----------------
__global__ __launch_bounds__(256)
void k_out(const u16* __restrict__ y, const float* __restrict__ Wout,
           const float* __restrict__ bout, float* __restrict__ outp)
{
    int c0 = blockIdx.x * 64;
    int r0 = blockIdx.y * 64;
    __shared__ u16 as [64][40] __attribute__((aligned(16)));
    __shared__ u16 ws [64][40] __attribute__((aligned(16)));  // ws[n][k] = Wout[k][c0+n]
    int t = threadIdx.x;
    int lane = t & 63, wv = t >> 6;
    int lr = lane & 15, lg = lane >> 4;
    int sr = t >> 2, sc = (t & 3) * 8;   // as stage: 64 rows x 32 k (bf16 direct)
    int wr = t >> 3, wc = (t & 7) * 8;   // ws stage: 32 k-rows x 64 n
    f32x4 acc[4] = {};
    for (int d0 = 0; d0 < Dd; d0 += 32) {
        ushort4 a0 = *(const ushort4*)(y + (size_t)(r0 + sr) * Dd + d0 + sc);
        ushort4 a1 = *(const ushort4*)(y + (size_t)(r0 + sr) * Dd + d0 + sc + 4);
        float4 wa = *(const float4*)(Wout + (size_t)(d0 + wr) * Dd + c0 + wc);
        float4 wb = *(const float4*)(Wout + (size_t)(d0 + wr) * Dd + c0 + wc + 4);
        __syncthreads();  // previous-iter LDS reads done before overwrite
        *(ushort4*)&as[sr][sc]     = a0;
        *(ushort4*)&as[sr][sc + 4] = a1;
        ws[wc+0][wr] = f2bs(wa.x); ws[wc+1][wr] = f2bs(wa.y);
        ws[wc+2][wr] = f2bs(wa.z); ws[wc+3][wr] = f2bs(wa.w);
        ws[wc+4][wr] = f2bs(wb.x); ws[wc+5][wr] = f2bs(wb.y);
        ws[wc+6][wr] = f2bs(wb.z); ws[wc+7][wr] = f2bs(wb.w);
        __syncthreads();
        bf16x8 a = *(const bf16x8*)&as[wv * 16 + lr][lg * 8];
        #pragma unroll
        for (int nt = 0; nt < 4; nt++) {
            bf16x8 bfr = *(const bf16x8*)&ws[nt * 16 + lr][lg * 8];
            acc[nt] = __builtin_amdgcn_mfma_f32_16x16x32_bf16(a, bfr, acc[nt], 0, 0, 0);
        }
    }
    // C/D layout: col = lane&15, row = (lane>>4)*4 + reg
    #pragma unroll
    for (int nt = 0; nt < 4; nt++) {
        float bias = bout[c0 + nt * 16 + lr];
        #pragma unroll
        for (int r = 0; r < 4; r++)
            outp[(size_t)(r0 + wv * 16 + lg * 4 + r) * Dd + c0 + nt * 16 + lr] =
                acc[nt][r] + bias;
    }
}

extern "C" void kernel_launch(void* const* d_in, const int* in_sizes, int n_in,
                              void* d_out, int out_size, void* d_ws, size_t ws_size,
                              hipStream_t stream)
{
    const float* x    = (const float*)d_in[0];
    const float* Qb   = (const float*)d_in[1];
    const float* Wq   = (const float*)d_in[2];
    const float* Wctx = (const float*)d_in[3];
    const float* bctx = (const float*)d_in[4];
    const float* Wout = (const float*)d_in[5];
    const float* bout = (const float*)d_in[6];
    const float* cent = (const float*)d_in[7];

    float* out     = (float*)d_out;
    float* out_cls = out + (size_t)Bc * Nn * Dd;
    float* out_idx = out_cls + (size_t)Bc * Dd;

    // ws layout: [idx(1KB)] [scores fp32 33.5MB / kvb bf16 26.1MB (reused)] [ctx fp32 26.2MB] [q/y bf16 101.2MB (aliased)]
    const size_t SC_B  = (size_t)Bc * Kk * Pp * 4;   // 33,554,432
    const size_t CTX_B = (size_t)Bc * CTX * Dd * 4;  // 26,148,864
    const size_t Y_B   = (size_t)Bc * Nn * Dd * 2;   // 101,154,816
    const size_t NEED  = 1024 + SC_B + CTX_B + Y_B;  // 160,859,136
    if (ws_size < NEED) return;  // fail loudly (zero outputs) rather than corrupt memory

    char* w = (char*)d_ws;
    int*   idx_i  = (int*)w;
    float* scores = (float*)(w + 1024);
    u16*   kvb    = (u16*)(w + 1024);               // reuses scores region after K4
    float* ctx    = (float*)(w + 1024 + SC_B);
    u16*   qy     = (u16*)(w + 1024 + SC_B + CTX_B); // q written by k_q, overwritten with y by k_attn

    k_cls    <<<Bc, 256, 0, stream>>>(x, cent, out_cls, out_idx, idx_i);
    k_q      <<<dim3(12, 1029), 256, 0, stream>>>(x, Wq, qy);
    k_scores <<<dim3(16, 2, Bc), 256, 0, stream>>>(x, Qb, idx_i, scores);
    k_softmax<<<Bc * Kk, 256, 0, stream>>>(scores);
    k_ctxp   <<<dim3(12, 2, Bc), 256, 0, stream>>>(scores, x, ctx);
    k_xreg   <<<Bc, 256, 0, stream>>>(x, ctx);
    k_kv     <<<dim3(24, 3, Bc), 256, 0, stream>>>(ctx, Wctx, bctx, kvb);
    k_attn   <<<dim3(17, Hh, Bc), 256, 0, stream>>>(kvb, qy);
    k_out    <<<dim3(12, 1029), 256, 0, stream>>>(qy, Wout, bout, out);
}

// Round 3
// 1318.779 us; speedup vs baseline: 5.3014x; 1.3459x over previous
//
#include <hip/hip_runtime.h>
#include <hip/hip_bf16.h>

#define Bc 64
#define Nn 1029
#define Dd 768
#define Hh 12
#define DH 64
#define Kk 128
#define Rr 5
#define Mm 4
#define Pp 1024
#define CTX 133
#define TWO_D 1536

typedef unsigned short u16;
typedef __attribute__((ext_vector_type(8))) short bf16x8;   // 8 bf16 = 4 VGPRs
typedef __attribute__((ext_vector_type(4))) float f32x4;

__device__ __forceinline__ float bs2f(u16 u){
    union { unsigned int i; float f; } c; c.i = ((unsigned)u) << 16; return c.f;
}
__device__ __forceinline__ u16 f2bs(float f){
    unsigned int u = __float_as_uint(f);
    unsigned int r = (u + 0x7fffu + ((u >> 16) & 1u)) >> 16;  // RNE
    return (u16)r;
}

#define FMA16(acc, a, b4) do { \
    acc[0][0] += a.x*b4.x; acc[0][1] += a.x*b4.y; acc[0][2] += a.x*b4.z; acc[0][3] += a.x*b4.w; \
    acc[1][0] += a.y*b4.x; acc[1][1] += a.y*b4.y; acc[1][2] += a.y*b4.z; acc[1][3] += a.y*b4.w; \
    acc[2][0] += a.z*b4.x; acc[2][1] += a.z*b4.y; acc[2][2] += a.z*b4.z; acc[2][3] += a.z*b4.w; \
    acc[3][0] += a.w*b4.x; acc[3][1] += a.w*b4.y; acc[3][2] += a.w*b4.z; acc[3][3] += a.w*b4.w; \
} while(0)

// ---------------- K1: cls_n + argmax idx ----------------
__global__ __launch_bounds__(256)
void k_cls(const float* __restrict__ x, const float* __restrict__ cent,
           float* __restrict__ out_cls, float* __restrict__ out_idx,
           int* __restrict__ idx_i)
{
    int b = blockIdx.x, t = threadIdx.x;
    const float* xr = x + (size_t)b * Nn * Dd;
    __shared__ float sx[Dd];
    __shared__ float wred[4];
    float ss = 0.f;
    for (int i = t; i < Dd; i += 256) { float v = xr[i]; sx[i] = v; ss += v * v; }
    for (int o = 32; o > 0; o >>= 1) ss += __shfl_down(ss, o);
    int lane = t & 63, wid = t >> 6;
    if (lane == 0) wred[wid] = ss;
    __syncthreads();
    float tot = wred[0] + wred[1] + wred[2] + wred[3];
    float inv = 1.f / fmaxf(sqrtf(tot), 1e-12f);
    __syncthreads();
    for (int i = t; i < Dd; i += 256) { float v = sx[i] * inv; sx[i] = v; out_cls[(size_t)b * Dd + i] = v; }
    __syncthreads();
    float sm[Mm];
    for (int m = 0; m < Mm; m++) {
        float s = 0.f;
        for (int i = t; i < Dd; i += 256) s += sx[i] * cent[m * Dd + i];
        for (int o = 32; o > 0; o >>= 1) s += __shfl_down(s, o);
        __syncthreads();
        if (lane == 0) wred[wid] = s;
        __syncthreads();
        sm[m] = wred[0] + wred[1] + wred[2] + wred[3];
    }
    if (t == 0) {
        int best = 0; float bv = sm[0];
        for (int m = 1; m < Mm; m++) if (sm[m] > bv) { bv = sm[m]; best = m; }
        idx_i[b] = best;
        out_idx[b] = (float)best;
    }
}

// ---------------- K1b: one-time weight transpose+bf16: WT[n][k] = bf16(W[k][n]) ----------------
__global__ __launch_bounds__(256)
void k_prep(const float* __restrict__ W, u16* __restrict__ WT, int K, int N)
{
    int k0 = blockIdx.x * 64;
    int n0 = blockIdx.y * 64;
    __shared__ float S[64][65];
    int t = threadIdx.x;
    int rr = t >> 4, c4 = (t & 15) * 4;
    #pragma unroll
    for (int i = 0; i < 4; i++) {
        float4 v = *(const float4*)(W + (size_t)(k0 + i * 16 + rr) * N + n0 + c4);
        S[i*16+rr][c4+0] = v.x; S[i*16+rr][c4+1] = v.y;
        S[i*16+rr][c4+2] = v.z; S[i*16+rr][c4+3] = v.w;
    }
    __syncthreads();
    #pragma unroll
    for (int i = 0; i < 4; i++) {
        int nn = i * 16 + rr;
        ushort4 o;
        o.x = f2bs(S[c4+0][nn]); o.y = f2bs(S[c4+1][nn]);
        o.z = f2bs(S[c4+2][nn]); o.w = f2bs(S[c4+3][nn]);
        *(ushort4*)(WT + (size_t)(n0 + nn) * K + k0 + c4) = o;
    }
}

// ---------------- K2: scores = Q_banks[idx] @ xp^T  (NT GEMM, fp32) ----------------
__global__ __launch_bounds__(256)
void k_scores(const float* __restrict__ x, const float* __restrict__ Qb,
              const int* __restrict__ idx_i, float* __restrict__ scores)
{
    int b = blockIdx.z;
    int k0 = blockIdx.y * 64;
    int p0 = blockIdx.x * 64;
    const float* A  = Qb + (size_t)idx_i[b] * Kk * Dd + (size_t)k0 * Dd;
    const float* Bm = x + (size_t)b * Nn * Dd + (size_t)Rr * Dd + (size_t)p0 * Dd;
    __shared__ float As[16][68] __attribute__((aligned(16)));
    __shared__ float Bs[16][68] __attribute__((aligned(16)));
    int t = threadIdx.x, tx = t & 15, ty = t >> 4;
    int lrow = t >> 2, lc4 = (t & 3) * 4;
    float acc[4][4] = {};
    for (int d0 = 0; d0 < Dd; d0 += 16) {
        float4 av = *(const float4*)(A  + (size_t)lrow * Dd + d0 + lc4);
        float4 bv = *(const float4*)(Bm + (size_t)lrow * Dd + d0 + lc4);
        As[lc4+0][lrow] = av.x; As[lc4+1][lrow] = av.y;
        As[lc4+2][lrow] = av.z; As[lc4+3][lrow] = av.w;
        Bs[lc4+0][lrow] = bv.x; Bs[lc4+1][lrow] = bv.y;
        Bs[lc4+2][lrow] = bv.z; Bs[lc4+3][lrow] = bv.w;
        __syncthreads();
        #pragma unroll
        for (int kk = 0; kk < 16; kk++) {
            float4 a  = *(const float4*)&As[kk][ty * 4];
            float4 b4 = *(const float4*)&Bs[kk][tx * 4];
            FMA16(acc, a, b4);
        }
        __syncthreads();
    }
    float* C = scores + ((size_t)b * Kk + k0) * Pp + p0;
    #pragma unroll
    for (int i = 0; i < 4; i++) {
        float4 v = make_float4(acc[i][0], acc[i][1], acc[i][2], acc[i][3]);
        *(float4*)(C + (size_t)(ty * 4 + i) * Pp + tx * 4) = v;
    }
}

// ---------------- K3: softmax rows of scores ----------------
__global__ __launch_bounds__(256)
void k_softmax(float* __restrict__ scores)
{
    size_t row = blockIdx.x;
    float* s = scores + row * Pp;
    int t = threadIdx.x;
    float v[4];
    float mx = -3.4e38f;
    #pragma unroll
    for (int j = 0; j < 4; j++) { v[j] = s[t + j * 256]; mx = fmaxf(mx, v[j]); }
    for (int o = 32; o > 0; o >>= 1) mx = fmaxf(mx, __shfl_down(mx, o));
    __shared__ float wred[4];
    int lane = t & 63, wid = t >> 6;
    if (lane == 0) wred[wid] = mx;
    __syncthreads();
    mx = fmaxf(fmaxf(wred[0], wred[1]), fmaxf(wred[2], wred[3]));
    float sum = 0.f;
    #pragma unroll
    for (int j = 0; j < 4; j++) { v[j] = __expf(v[j] - mx); sum += v[j]; }
    for (int o = 32; o > 0; o >>= 1) sum += __shfl_down(sum, o);
    __syncthreads();
    if (lane == 0) wred[wid] = sum;
    __syncthreads();
    sum = wred[0] + wred[1] + wred[2] + wred[3];
    float inv = 1.f / sum;
    #pragma unroll
    for (int j = 0; j < 4; j++) s[t + j * 256] = v[j] * inv;
}

// ---------------- K4: ctx_p = attn @ xp  (NN GEMM, fp32) ----------------
__global__ __launch_bounds__(256)
void k_ctxp(const float* __restrict__ scores, const float* __restrict__ x,
            float* __restrict__ ctx)
{
    int b = blockIdx.z;
    int k0 = blockIdx.y * 64;
    int c0 = blockIdx.x * 64;
    const float* A  = scores + ((size_t)b * Kk + k0) * Pp;
    const float* Bm = x + (size_t)b * Nn * Dd + (size_t)Rr * Dd;
    __shared__ float As[16][68] __attribute__((aligned(16)));
    __shared__ float Bs[16][68] __attribute__((aligned(16)));
    int t = threadIdx.x, tx = t & 15, ty = t >> 4;
    int arow = t >> 2, ac4 = (t & 3) * 4;
    int brow = t >> 4, bc4 = (t & 15) * 4;
    float acc[4][4] = {};
    for (int p0 = 0; p0 < Pp; p0 += 16) {
        float4 av = *(const float4*)(A + (size_t)arow * Pp + p0 + ac4);
        As[ac4+0][arow] = av.x; As[ac4+1][arow] = av.y;
        As[ac4+2][arow] = av.z; As[ac4+3][arow] = av.w;
        float4 bv = *(const float4*)(Bm + (size_t)(p0 + brow) * Dd + c0 + bc4);
        Bs[brow][bc4+0] = bv.x; Bs[brow][bc4+1] = bv.y;
        Bs[brow][bc4+2] = bv.z; Bs[brow][bc4+3] = bv.w;
        __syncthreads();
        #pragma unroll
        for (int kk = 0; kk < 16; kk++) {
            float4 a  = *(const float4*)&As[kk][ty * 4];
            float4 b4 = *(const float4*)&Bs[kk][tx * 4];
            FMA16(acc, a, b4);
        }
        __syncthreads();
    }
    float* C = ctx + ((size_t)b * CTX + Rr + k0) * Dd + c0;
    #pragma unroll
    for (int i = 0; i < 4; i++) {
        float4 v = make_float4(acc[i][0], acc[i][1], acc[i][2], acc[i][3]);
        *(float4*)(C + (size_t)(ty * 4 + i) * Dd + tx * 4) = v;
    }
}

// ---------------- K4b: copy xreg rows into ctx ----------------
__global__ __launch_bounds__(256)
void k_xreg(const float* __restrict__ x, float* __restrict__ ctx)
{
    int b = blockIdx.x, t = threadIdx.x;
    const float* src = x + (size_t)b * Nn * Dd;
    float* dst = ctx + (size_t)b * CTX * Dd;
    for (int i = t; i < Rr * Dd; i += 256) dst[i] = src[i];
}

// ---------------- K5: kv = ctx @ Wctx + bctx  (bf16 MFMA, fp32 in via cvt, bf16 out) ----------------
__global__ __launch_bounds__(256)
void k_kv(const float* __restrict__ ctx, const float* __restrict__ Wctx,
          const float* __restrict__ bctx, u16* __restrict__ kvb)
{
    int c0 = blockIdx.x * 64;   // 24 tiles over TWO_D=1536
    int m0 = blockIdx.y * 64;   // 3 tiles over CTX=133 (tail clamped/masked)
    int b  = blockIdx.z;
    const float* A = ctx + (size_t)b * CTX * Dd;
    __shared__ u16 as [64][40] __attribute__((aligned(16)));
    __shared__ u16 ws [64][40] __attribute__((aligned(16)));  // ws[n][k] = Wctx[k][c0+n]
    int t = threadIdx.x;
    int lane = t & 63, wv = t >> 6;
    int lr = lane & 15, lg = lane >> 4;
    int sr = t >> 2, sc = (t & 3) * 8;   // as stage: 64 rows x 32 k
    int wr = t >> 3, wc = (t & 7) * 8;   // ws stage: 32 k-rows x 64 n
    int am = m0 + sr; if (am >= CTX) am = CTX - 1;   // clamp tail rows (stores masked)
    f32x4 acc[4] = {};
    for (int d0 = 0; d0 < Dd; d0 += 32) {
        float4 xa = *(const float4*)(A + (size_t)am * Dd + d0 + sc);
        float4 xb = *(const float4*)(A + (size_t)am * Dd + d0 + sc + 4);
        float4 wa = *(const float4*)(Wctx + (size_t)(d0 + wr) * TWO_D + c0 + wc);
        float4 wb = *(const float4*)(Wctx + (size_t)(d0 + wr) * TWO_D + c0 + wc + 4);
        __syncthreads();  // previous-iter LDS reads done before overwrite
        ushort4 x0; x0.x = f2bs(xa.x); x0.y = f2bs(xa.y); x0.z = f2bs(xa.z); x0.w = f2bs(xa.w);
        ushort4 x1; x1.x = f2bs(xb.x); x1.y = f2bs(xb.y); x1.z = f2bs(xb.z); x1.w = f2bs(xb.w);
        *(ushort4*)&as[sr][sc]     = x0;
        *(ushort4*)&as[sr][sc + 4] = x1;
        ws[wc+0][wr] = f2bs(wa.x); ws[wc+1][wr] = f2bs(wa.y);
        ws[wc+2][wr] = f2bs(wa.z); ws[wc+3][wr] = f2bs(wa.w);
        ws[wc+4][wr] = f2bs(wb.x); ws[wc+5][wr] = f2bs(wb.y);
        ws[wc+6][wr] = f2bs(wb.z); ws[wc+7][wr] = f2bs(wb.w);
        __syncthreads();
        bf16x8 a = *(const bf16x8*)&as[wv * 16 + lr][lg * 8];
        #pragma unroll
        for (int nt = 0; nt < 4; nt++) {
            bf16x8 bfr = *(const bf16x8*)&ws[nt * 16 + lr][lg * 8];
            acc[nt] = __builtin_amdgcn_mfma_f32_16x16x32_bf16(a, bfr, acc[nt], 0, 0, 0);
        }
    }
    // C/D layout: col = lane&15, row = (lane>>4)*4 + reg
    #pragma unroll
    for (int nt = 0; nt < 4; nt++) {
        float bias = bctx[c0 + nt * 16 + lr];
        #pragma unroll
        for (int r = 0; r < 4; r++) {
            int m = m0 + wv * 16 + lg * 4 + r;
            if (m < CTX)
                kvb[((size_t)b * CTX + m) * TWO_D + c0 + nt * 16 + lr] =
                    f2bs(acc[nt][r] + bias);
        }
    }
}

// ---------------- K6a: q = (x @ Wq) * 0.125 -> bf16 into qy ----------------
// 64x256 tile/block, 4 waves each 64x64 (4x4 fragment grid). Double-buffered LDS,
// register prefetch, XCD-grouped swizzle: the 3 c-tiles of a row-panel share an XCD/L2.
__global__ __launch_bounds__(256)
void k_q(const float* __restrict__ x, const u16* __restrict__ WqT,
         u16* __restrict__ q)
{
    int p = blockIdx.x;
    int within = p % 24;
    int ct = within >> 3;                       // 0..2 (256-col tile)
    int rt = (p / 24) * 8 + (within & 7);       // row-tile; same row -> same XCD slot
    if (rt >= 1029) return;
    int r0 = rt * 64;
    int c0 = ct * 256;

    __shared__ u16 As[2][64][40]  __attribute__((aligned(16)));
    __shared__ u16 Bs[2][256][40] __attribute__((aligned(16)));

    int t = threadIdx.x;
    int lane = t & 63, wv = t >> 6;
    int lr = lane & 15, lg = lane >> 4;
    int sr = t >> 2, sc = (t & 3) * 8;          // stage coords: row, k-offset

    const float* xr = x + (size_t)(r0 + sr) * Dd + sc;
    const u16*   wr = WqT + (size_t)(c0 + sr) * Dd + sc;

    f32x4 acc[4][4] = {};                        // [mt][nt]
    float4 xa, xb;
    bf16x8 wb0, wb1, wb2, wb3;

    // prologue: load + stage chunk 0
    xa = *(const float4*)(xr + 0);
    xb = *(const float4*)(xr + 4);
    wb0 = *(const bf16x8*)(wr + 0 * 64 * Dd);
    wb1 = *(const bf16x8*)(wr + 1 * 64 * Dd);
    wb2 = *(const bf16x8*)(wr + 2 * 64 * Dd);
    wb3 = *(const bf16x8*)(wr + 3 * 64 * Dd);
    {
        bf16x8 av; av[0]=f2bs(xa.x); av[1]=f2bs(xa.y); av[2]=f2bs(xa.z); av[3]=f2bs(xa.w);
        av[4]=f2bs(xb.x); av[5]=f2bs(xb.y); av[6]=f2bs(xb.z); av[7]=f2bs(xb.w);
        *(bf16x8*)&As[0][sr][sc] = av;
        *(bf16x8*)&Bs[0][0*64+sr][sc] = wb0;
        *(bf16x8*)&Bs[0][1*64+sr][sc] = wb1;
        *(bf16x8*)&Bs[0][2*64+sr][sc] = wb2;
        *(bf16x8*)&Bs[0][3*64+sr][sc] = wb3;
    }
    int cur = 0;
    for (int it = 0; it < 24; ++it) {
        int d1 = (it + 1) * 32;
        if (it < 23) {                           // issue next-chunk global loads early
            xa = *(const float4*)(xr + d1 + 0);
            xb = *(const float4*)(xr + d1 + 4);
            wb0 = *(const bf16x8*)(wr + 0 * 64 * Dd + d1);
            wb1 = *(const bf16x8*)(wr + 1 * 64 * Dd + d1);
            wb2 = *(const bf16x8*)(wr + 2 * 64 * Dd + d1);
            wb3 = *(const bf16x8*)(wr + 3 * 64 * Dd + d1);
        }
        __syncthreads();                          // buf[cur] ready
        bf16x8 af[4], bf[4];
        #pragma unroll
        for (int mt = 0; mt < 4; mt++) af[mt] = *(const bf16x8*)&As[cur][mt * 16 + lr][lg * 8];
        #pragma unroll
        for (int nt = 0; nt < 4; nt++) bf[nt] = *(const bf16x8*)&Bs[cur][wv * 64 + nt * 16 + lr][lg * 8];
        #pragma unroll
        for (int mt = 0; mt < 4; mt++)
            #pragma unroll
            for (int nt = 0; nt < 4; nt++)
                acc[mt][nt] = __builtin_amdgcn_mfma_f32_16x16x32_bf16(af[mt], bf[nt], acc[mt][nt], 0, 0, 0);
        if (it < 23) {                            // write next buf (visible after next barrier)
            bf16x8 av; av[0]=f2bs(xa.x); av[1]=f2bs(xa.y); av[2]=f2bs(xa.z); av[3]=f2bs(xa.w);
            av[4]=f2bs(xb.x); av[5]=f2bs(xb.y); av[6]=f2bs(xb.z); av[7]=f2bs(xb.w);
            int nb = cur ^ 1;
            *(bf16x8*)&As[nb][sr][sc] = av;
            *(bf16x8*)&Bs[nb][0*64+sr][sc] = wb0;
            *(bf16x8*)&Bs[nb][1*64+sr][sc] = wb1;
            *(bf16x8*)&Bs[nb][2*64+sr][sc] = wb2;
            *(bf16x8*)&Bs[nb][3*64+sr][sc] = wb3;
        }
        cur ^= 1;
    }
    // C/D layout: col = lane&15, row = (lane>>4)*4 + reg
    #pragma unroll
    for (int mt = 0; mt < 4; mt++)
        #pragma unroll
        for (int nt = 0; nt < 4; nt++)
            #pragma unroll
            for (int r = 0; r < 4; r++)
                q[(size_t)(r0 + mt * 16 + lg * 4 + r) * Dd + c0 + wv * 64 + nt * 16 + lr] =
                    f2bs(acc[mt][nt][r] * 0.125f);
}

// ---------------- K6b: attention via MFMA: logits -> softmax -> PV, overwrites q with y ----------------
// Block: one (b, h), 64 q-rows (4 waves x 16). CTX=133 padded to 144 (QK tiles) / 160 (PV k-dim).
__global__ __launch_bounds__(256)
void k_attn(const u16* __restrict__ kvb, u16* __restrict__ qy)
{
    int n0 = blockIdx.x * 64;
    int h  = blockIdx.y;
    int b  = blockIdx.z;
    int t = threadIdx.x;
    int lane = t & 63, wv = t >> 6;
    int lr = lane & 15, lg = lane >> 4;

    __shared__ u16 ks [144][72]      __attribute__((aligned(16)));  // K rows, stride 144B
    __shared__ u16 vst[64][168]      __attribute__((aligned(16)));  // V^T: [dh][p], stride 336B
    __shared__ u16 ps [4][16][168]   __attribute__((aligned(16)));  // per-wave P (bf16)

    // ---- load this wave's q fragments (must precede the y overwrite; same buffer) ----
    int qn = n0 + wv * 16 + lr;
    size_t qrow = (size_t)b * Nn + (qn < Nn ? qn : Nn - 1);
    bf16x8 aq0 = *(const bf16x8*)(qy + qrow * Dd + h * DH + lg * 8);
    bf16x8 aq1 = *(const bf16x8*)(qy + qrow * Dd + h * DH + 32 + lg * 8);

    // ---- stage K (row-major) and V (transposed) into LDS; zero the pads ----
    const u16* kvrow = kvb + (size_t)b * CTX * TWO_D + h * DH;
    for (int e4 = t * 4; e4 < CTX * DH; e4 += 1024) {
        int m = e4 >> 6, dd = e4 & 63;
        *(ushort4*)&ks[m][dd] = *(const ushort4*)(kvrow + (size_t)m * TWO_D + dd);
        ushort4 vv = *(const ushort4*)(kvrow + (size_t)m * TWO_D + Dd + dd);
        vst[dd + 0][m] = vv.x; vst[dd + 1][m] = vv.y;
        vst[dd + 2][m] = vv.z; vst[dd + 3][m] = vv.w;
    }
    for (int i = t; i < 11 * 64; i += 256) ks[133 + (i >> 6)][i & 63] = 0;    // K rows 133..143
    for (int i = t; i < 64 * 27; i += 256) vst[i / 27][133 + i % 27] = 0;     // V^T cols 133..159
    for (int i = t; i < 64 * 16; i += 256) {                                  // P cols 144..159
        int rr = i >> 4;
        ps[rr >> 4][rr & 15][144 + (i & 15)] = 0;
    }
    __syncthreads();

    // ---- QK^T: 9 n-tiles of 16 k-rows; k-dim = 64 = 2 mfma ----
    f32x4 stile[9];
    #pragma unroll
    for (int tn = 0; tn < 9; tn++) {
        bf16x8 bk0 = *(const bf16x8*)&ks[tn * 16 + lr][lg * 8];
        bf16x8 bk1 = *(const bf16x8*)&ks[tn * 16 + lr][32 + lg * 8];
        f32x4 a = {0.f, 0.f, 0.f, 0.f};
        a = __builtin_amdgcn_mfma_f32_16x16x32_bf16(aq0, bk0, a, 0, 0, 0);
        a = __builtin_amdgcn_mfma_f32_16x16x32_bf16(aq1, bk1, a, 0, 0, 0);
        stile[tn] = a;
    }

    // ---- softmax per output row; row m's 144 logits live in the 16 lanes of this lg-group ----
    #pragma unroll
    for (int r = 0; r < 4; r++) {
        float m_ = -3.4e38f;
        #pragma unroll
        for (int tn = 0; tn < 9; tn++) {
            float v = stile[tn][r];
            if (tn == 8 && lr >= 5) v = -3.4e38f;   // n = 128 + lr >= 133 -> masked
            m_ = fmaxf(m_, v);
        }
        m_ = fmaxf(m_, __shfl_xor(m_, 1));
        m_ = fmaxf(m_, __shfl_xor(m_, 2));
        m_ = fmaxf(m_, __shfl_xor(m_, 4));
        m_ = fmaxf(m_, __shfl_xor(m_, 8));
        float pv[9];
        float s_ = 0.f;
        #pragma unroll
        for (int tn = 0; tn < 9; tn++) {
            float v = stile[tn][r];
            v = (tn == 8 && lr >= 5) ? 0.f : __expf(v - m_);
            pv[tn] = v; s_ += v;
        }
        s_ += __shfl_xor(s_, 1);
        s_ += __shfl_xor(s_, 2);
        s_ += __shfl_xor(s_, 4);
        s_ += __shfl_xor(s_, 8);
        float inv = 1.f / s_;
        #pragma unroll
        for (int tn = 0; tn < 9; tn++)
            ps[wv][lg * 4 + r][tn * 16 + lr] = f2bs(pv[tn] * inv);
    }
    __syncthreads();   // ps (incl. zero pads) visible before PV fragment reads

    // ---- PV: y[16 x 64] = P[16 x 160] @ V[160 x 64] (V^T rows as B-fragments) ----
    f32x4 yacc[4] = {};
    #pragma unroll
    for (int kk = 0; kk < 5; kk++) {
        bf16x8 ap = *(const bf16x8*)&ps[wv][lr][kk * 32 + lg * 8];
        #pragma unroll
        for (int td = 0; td < 4; td++) {
            bf16x8 bv = *(const bf16x8*)&vst[td * 16 + lr][kk * 32 + lg * 8];
            yacc[td] = __builtin_amdgcn_mfma_f32_16x16x32_bf16(ap, bv, yacc[td], 0, 0, 0);
        }
    }

    // ---- store y (overwrites this block's q region; q already consumed) ----
    #pragma unroll
    for (int td = 0; td < 4; td++)
        #pragma unroll
        for (int r = 0; r < 4; r++) {
            int gn = n0 + wv * 16 + lg * 4 + r;
            if (gn < Nn)
                qy[((size_t)b * Nn + gn) * Dd + h * DH + td * 16 + lr] = f2bs(yacc[td][r]);
        }
}

// ---------------- K7: out = y @ Wout + bout  (bf16 MFMA; same structure as k_q) ----------------
__global__ __launch_bounds__(256)
void k_out(const u16* __restrict__ y, const u16* __restrict__ WoT,
           const float* __restrict__ bout, float* __restrict__ outp)
{
    int p = blockIdx.x;
    int within = p % 24;
    int ct = within >> 3;
    int rt = (p / 24) * 8 + (within & 7);
    if (rt >= 1029) return;
    int r0 = rt * 64;
    int c0 = ct * 256;

    __shared__ u16 As[2][64][40]  __attribute__((aligned(16)));
    __shared__ u16 Bs[2][256][40] __attribute__((aligned(16)));

    int t = threadIdx.x;
    int lane = t & 63, wv = t >> 6;
    int lr = lane & 15, lg = lane >> 4;
    int sr = t >> 2, sc = (t & 3) * 8;

    const u16* yr = y + (size_t)(r0 + sr) * Dd + sc;
    const u16* wr = WoT + (size_t)(c0 + sr) * Dd + sc;

    f32x4 acc[4][4] = {};
    bf16x8 av, wb0, wb1, wb2, wb3;

    av  = *(const bf16x8*)(yr + 0);
    wb0 = *(const bf16x8*)(wr + 0 * 64 * Dd);
    wb1 = *(const bf16x8*)(wr + 1 * 64 * Dd);
    wb2 = *(const bf16x8*)(wr + 2 * 64 * Dd);
    wb3 = *(const bf16x8*)(wr + 3 * 64 * Dd);
    *(bf16x8*)&As[0][sr][sc] = av;
    *(bf16x8*)&Bs[0][0*64+sr][sc] = wb0;
    *(bf16x8*)&Bs[0][1*64+sr][sc] = wb1;
    *(bf16x8*)&Bs[0][2*64+sr][sc] = wb2;
    *(bf16x8*)&Bs[0][3*64+sr][sc] = wb3;

    int cur = 0;
    for (int it = 0; it < 24; ++it) {
        int d1 = (it + 1) * 32;
        if (it < 23) {
            av  = *(const bf16x8*)(yr + d1);
            wb0 = *(const bf16x8*)(wr + 0 * 64 * Dd + d1);
            wb1 = *(const bf16x8*)(wr + 1 * 64 * Dd + d1);
            wb2 = *(const bf16x8*)(wr + 2 * 64 * Dd + d1);
            wb3 = *(const bf16x8*)(wr + 3 * 64 * Dd + d1);
        }
        __syncthreads();
        bf16x8 af[4], bf[4];
        #pragma unroll
        for (int mt = 0; mt < 4; mt++) af[mt] = *(const bf16x8*)&As[cur][mt * 16 + lr][lg * 8];
        #pragma unroll
        for (int nt = 0; nt < 4; nt++) bf[nt] = *(const bf16x8*)&Bs[cur][wv * 64 + nt * 16 + lr][lg * 8];
        #pragma unroll
        for (int mt = 0; mt < 4; mt++)
            #pragma unroll
            for (int nt = 0; nt < 4; nt++)
                acc[mt][nt] = __builtin_amdgcn_mfma_f32_16x16x32_bf16(af[mt], bf[nt], acc[mt][nt], 0, 0, 0);
        if (it < 23) {
            int nb = cur ^ 1;
            *(bf16x8*)&As[nb][sr][sc] = av;
            *(bf16x8*)&Bs[nb][0*64+sr][sc] = wb0;
            *(bf16x8*)&Bs[nb][1*64+sr][sc] = wb1;
            *(bf16x8*)&Bs[nb][2*64+sr][sc] = wb2;
            *(bf16x8*)&Bs[nb][3*64+sr][sc] = wb3;
        }
        cur ^= 1;
    }
    #pragma unroll
    for (int nt = 0; nt < 4; nt++) {
        float bias = bout[c0 + wv * 64 + nt * 16 + lr];
        #pragma unroll
        for (int mt = 0; mt < 4; mt++)
            #pragma unroll
            for (int r = 0; r < 4; r++)
                outp[(size_t)(r0 + mt * 16 + lg * 4 + r) * Dd + c0 + wv * 64 + nt * 16 + lr] =
                    acc[mt][nt][r] + bias;
    }
}

extern "C" void kernel_launch(void* const* d_in, const int* in_sizes, int n_in,
                              void* d_out, int out_size, void* d_ws, size_t ws_size,
                              hipStream_t stream)
{
    const float* x    = (const float*)d_in[0];
    const float* Qb   = (const float*)d_in[1];
    const float* Wq   = (const float*)d_in[2];
    const float* Wctx = (const float*)d_in[3];
    const float* bctx = (const float*)d_in[4];
    const float* Wout = (const float*)d_in[5];
    const float* bout = (const float*)d_in[6];
    const float* cent = (const float*)d_in[7];

    float* out     = (float*)d_out;
    float* out_cls = out + (size_t)Bc * Nn * Dd;
    float* out_idx = out_cls + (size_t)Bc * Dd;

    // ws layout: [idx(1KB)] [scores fp32 33.5MB / kvb bf16 26.1MB (reused)] [ctx fp32 26.2MB] [q/y bf16 101.2MB (aliased)]
    const size_t SC_B  = (size_t)Bc * Kk * Pp * 4;   // 33,554,432
    const size_t CTX_B = (size_t)Bc * CTX * Dd * 4;  // 26,148,864
    const size_t Y_B   = (size_t)Bc * Nn * Dd * 2;   // 101,154,816
    const size_t NEED  = 1024 + SC_B + CTX_B + Y_B;  // 160,859,136
    if (ws_size < NEED) return;  // fail loudly (zero outputs) rather than corrupt memory

    char* w = (char*)d_ws;
    int*   idx_i  = (int*)w;
    float* scores = (float*)(w + 1024);
    u16*   kvb    = (u16*)(w + 1024);               // reuses scores region after K4
    float* ctx    = (float*)(w + 1024 + SC_B);
    u16*   qy     = (u16*)(w + 1024 + SC_B + CTX_B); // q written by k_q, overwritten with y by k_attn

    // weight scratch carved from dead regions (zero extra workspace):
    //  WqT  -> out region (out untouched until k_out; cls/idx live past B*N*D)
    //  WoutT-> ctx region (ctx dead after k_kv)
    u16* WqT   = (u16*)out;
    u16* WoutT = (u16*)ctx;

    k_cls    <<<Bc, 256, 0, stream>>>(x, cent, out_cls, out_idx, idx_i);
    k_prep   <<<dim3(12, 12), 256, 0, stream>>>(Wq, WqT, Dd, Dd);
    k_q      <<<3096, 256, 0, stream>>>(x, WqT, qy);
    k_scores <<<dim3(16, 2, Bc), 256, 0, stream>>>(x, Qb, idx_i, scores);
    k_softmax<<<Bc * Kk, 256, 0, stream>>>(scores);
    k_ctxp   <<<dim3(12, 2, Bc), 256, 0, stream>>>(scores, x, ctx);
    k_xreg   <<<Bc, 256, 0, stream>>>(x, ctx);
    k_kv     <<<dim3(24, 3, Bc), 256, 0, stream>>>(ctx, Wctx, bctx, kvb);
    k_prep   <<<dim3(12, 12), 256, 0, stream>>>(Wout, WoutT, Dd, Dd);
    k_attn   <<<dim3(17, Hh, Bc), 256, 0, stream>>>(kvb, qy);
    k_out    <<<3096, 256, 0, stream>>>(qy, WoutT, bout, out);
}

// Round 4
// 1008.048 us; speedup vs baseline: 6.9355x; 1.3083x over previous
//
#include <hip/hip_runtime.h>
#include <hip/hip_bf16.h>

#define Bc 64
#define Nn 1029
#define Dd 768
#define Hh 12
#define DH 64
#define Kk 128
#define Rr 5
#define Mm 4
#define Pp 1024
#define CTX 133
#define TWO_D 1536

typedef unsigned short u16;
typedef __attribute__((ext_vector_type(8))) short bf16x8;   // 8 bf16 = 4 VGPRs
typedef __attribute__((ext_vector_type(4))) float f32x4;

__device__ __forceinline__ float bs2f(u16 u){
    union { unsigned int i; float f; } c; c.i = ((unsigned)u) << 16; return c.f;
}
__device__ __forceinline__ u16 f2bs(float f){
    unsigned int u = __float_as_uint(f);
    unsigned int r = (u + 0x7fffu + ((u >> 16) & 1u)) >> 16;  // RNE
    return (u16)r;
}
// packed f32x2 -> bf16x2 (RNE), single HW instr
__device__ __forceinline__ unsigned cvt2(float lo, float hi){
    unsigned r;
    asm("v_cvt_pk_bf16_f32 %0, %1, %2" : "=v"(r) : "v"(lo), "v"(hi));
    return r;
}
__device__ __forceinline__ bf16x8 pk8(float4 a, float4 b){
    union { unsigned u[4]; bf16x8 v; } c;
    c.u[0] = cvt2(a.x, a.y); c.u[1] = cvt2(a.z, a.w);
    c.u[2] = cvt2(b.x, b.y); c.u[3] = cvt2(b.z, b.w);
    return c.v;
}

// ---------------- K1: cls_n + argmax idx ----------------
__global__ __launch_bounds__(256)
void k_cls(const float* __restrict__ x, const float* __restrict__ cent,
           float* __restrict__ out_cls, float* __restrict__ out_idx,
           int* __restrict__ idx_i)
{
    int b = blockIdx.x, t = threadIdx.x;
    const float* xr = x + (size_t)b * Nn * Dd;
    __shared__ float sx[Dd];
    __shared__ float wred[4];
    float ss = 0.f;
    for (int i = t; i < Dd; i += 256) { float v = xr[i]; sx[i] = v; ss += v * v; }
    for (int o = 32; o > 0; o >>= 1) ss += __shfl_down(ss, o);
    int lane = t & 63, wid = t >> 6;
    if (lane == 0) wred[wid] = ss;
    __syncthreads();
    float tot = wred[0] + wred[1] + wred[2] + wred[3];
    float inv = 1.f / fmaxf(sqrtf(tot), 1e-12f);
    __syncthreads();
    for (int i = t; i < Dd; i += 256) { float v = sx[i] * inv; sx[i] = v; out_cls[(size_t)b * Dd + i] = v; }
    __syncthreads();
    float sm[Mm];
    for (int m = 0; m < Mm; m++) {
        float s = 0.f;
        for (int i = t; i < Dd; i += 256) s += sx[i] * cent[m * Dd + i];
        for (int o = 32; o > 0; o >>= 1) s += __shfl_down(s, o);
        __syncthreads();
        if (lane == 0) wred[wid] = s;
        __syncthreads();
        sm[m] = wred[0] + wred[1] + wred[2] + wred[3];
    }
    if (t == 0) {
        int best = 0; float bv = sm[0];
        for (int m = 1; m < Mm; m++) if (sm[m] > bv) { bv = sm[m]; best = m; }
        idx_i[b] = best;
        out_idx[b] = (float)best;
    }
}

// ---------------- K1b: one-time weight transpose+bf16: WT[n][k] = bf16(W[k][n]) ----------------
__global__ __launch_bounds__(256)
void k_prep(const float* __restrict__ W, u16* __restrict__ WT, int K, int N)
{
    int k0 = blockIdx.x * 64;
    int n0 = blockIdx.y * 64;
    __shared__ float S[64][65];
    int t = threadIdx.x;
    int rr = t >> 4, c4 = (t & 15) * 4;
    #pragma unroll
    for (int i = 0; i < 4; i++) {
        float4 v = *(const float4*)(W + (size_t)(k0 + i * 16 + rr) * N + n0 + c4);
        S[i*16+rr][c4+0] = v.x; S[i*16+rr][c4+1] = v.y;
        S[i*16+rr][c4+2] = v.z; S[i*16+rr][c4+3] = v.w;
    }
    __syncthreads();
    #pragma unroll
    for (int i = 0; i < 4; i++) {
        int nn = i * 16 + rr;
        ushort4 o;
        o.x = f2bs(S[c4+0][nn]); o.y = f2bs(S[c4+1][nn]);
        o.z = f2bs(S[c4+2][nn]); o.w = f2bs(S[c4+3][nn]);
        *(ushort4*)(WT + (size_t)(n0 + nn) * K + k0 + c4) = o;
    }
}

// ---------------- K2: scores = Q_banks[idx] @ xp^T  (bf16 MFMA, fp32 out) ----------------
// 64(M=k) x 256(N=p) tile, double-buffered, XOR-swizzled B rows.
__global__ __launch_bounds__(256)
void k_scores(const float* __restrict__ x, const float* __restrict__ Qb,
              const int* __restrict__ idx_i, float* __restrict__ scores)
{
    int p0 = blockIdx.x * 256;
    int k0 = blockIdx.y * 64;
    int b  = blockIdx.z;
    const float* A  = Qb + (size_t)idx_i[b] * Kk * Dd + (size_t)k0 * Dd;
    const float* Bm = x + (size_t)b * Nn * Dd + (size_t)Rr * Dd + (size_t)p0 * Dd;

    __shared__ u16 As[2][64][40]  __attribute__((aligned(16)));
    __shared__ u16 Bs[2][256][40] __attribute__((aligned(16)));

    int t = threadIdx.x;
    int lane = t & 63, wv = t >> 6;
    int lr = lane & 15, lg = lane >> 4;
    int sr = t >> 2, sc = (t & 3) * 8, jg = t & 3;

    f32x4 acc[4][4] = {};
    float4 pa0, pa1, pb[8];

    pa0 = *(const float4*)(A + (size_t)sr * Dd + sc);
    pa1 = *(const float4*)(A + (size_t)sr * Dd + sc + 4);
    #pragma unroll
    for (int g = 0; g < 4; g++) {
        pb[2*g]   = *(const float4*)(Bm + (size_t)(g * 64 + sr) * Dd + sc);
        pb[2*g+1] = *(const float4*)(Bm + (size_t)(g * 64 + sr) * Dd + sc + 4);
    }
    *(bf16x8*)&As[0][sr][sc] = pk8(pa0, pa1);
    #pragma unroll
    for (int g = 0; g < 4; g++) {
        int row = g * 64 + sr;
        *(bf16x8*)&Bs[0][row][(jg ^ ((row >> 3) & 3)) * 8] = pk8(pb[2*g], pb[2*g+1]);
    }
    int cur = 0;
    for (int it = 0; it < 24; ++it) {
        int d1 = (it + 1) * 32;
        if (it < 23) {
            pa0 = *(const float4*)(A + (size_t)sr * Dd + d1 + sc);
            pa1 = *(const float4*)(A + (size_t)sr * Dd + d1 + sc + 4);
            #pragma unroll
            for (int g = 0; g < 4; g++) {
                pb[2*g]   = *(const float4*)(Bm + (size_t)(g * 64 + sr) * Dd + d1 + sc);
                pb[2*g+1] = *(const float4*)(Bm + (size_t)(g * 64 + sr) * Dd + d1 + sc + 4);
            }
        }
        __syncthreads();
        bf16x8 af[4], bf[4];
        #pragma unroll
        for (int mt = 0; mt < 4; mt++) af[mt] = *(const bf16x8*)&As[cur][mt * 16 + lr][lg * 8];
        #pragma unroll
        for (int nt = 0; nt < 4; nt++) {
            int row = wv * 64 + nt * 16 + lr;
            bf[nt] = *(const bf16x8*)&Bs[cur][row][(lg ^ ((row >> 3) & 3)) * 8];
        }
        #pragma unroll
        for (int mt = 0; mt < 4; mt++)
            #pragma unroll
            for (int nt = 0; nt < 4; nt++)
                acc[mt][nt] = __builtin_amdgcn_mfma_f32_16x16x32_bf16(af[mt], bf[nt], acc[mt][nt], 0, 0, 0);
        if (it < 23) {
            int nb = cur ^ 1;
            *(bf16x8*)&As[nb][sr][sc] = pk8(pa0, pa1);
            #pragma unroll
            for (int g = 0; g < 4; g++) {
                int row = g * 64 + sr;
                *(bf16x8*)&Bs[nb][row][(jg ^ ((row >> 3) & 3)) * 8] = pk8(pb[2*g], pb[2*g+1]);
            }
        }
        cur ^= 1;
    }
    float* C = scores + ((size_t)b * Kk + k0) * Pp + p0;
    #pragma unroll
    for (int mt = 0; mt < 4; mt++)
        #pragma unroll
        for (int nt = 0; nt < 4; nt++)
            #pragma unroll
            for (int r = 0; r < 4; r++)
                C[(size_t)(mt * 16 + lg * 4 + r) * Pp + wv * 64 + nt * 16 + lr] = acc[mt][nt][r];
}

// ---------------- K3: softmax rows of scores ----------------
__global__ __launch_bounds__(256)
void k_softmax(float* __restrict__ scores)
{
    size_t row = blockIdx.x;
    float* s = scores + row * Pp;
    int t = threadIdx.x;
    float v[4];
    float mx = -3.4e38f;
    #pragma unroll
    for (int j = 0; j < 4; j++) { v[j] = s[t + j * 256]; mx = fmaxf(mx, v[j]); }
    for (int o = 32; o > 0; o >>= 1) mx = fmaxf(mx, __shfl_down(mx, o));
    __shared__ float wred[4];
    int lane = t & 63, wid = t >> 6;
    if (lane == 0) wred[wid] = mx;
    __syncthreads();
    mx = fmaxf(fmaxf(wred[0], wred[1]), fmaxf(wred[2], wred[3]));
    float sum = 0.f;
    #pragma unroll
    for (int j = 0; j < 4; j++) { v[j] = __expf(v[j] - mx); sum += v[j]; }
    for (int o = 32; o > 0; o >>= 1) sum += __shfl_down(sum, o);
    __syncthreads();
    if (lane == 0) wred[wid] = sum;
    __syncthreads();
    sum = wred[0] + wred[1] + wred[2] + wred[3];
    float inv = 1.f / sum;
    #pragma unroll
    for (int j = 0; j < 4; j++) s[t + j * 256] = v[j] * inv;
}

// ---------------- K4: ctx_p = attn @ xp  (bf16 MFMA, fp32 out; xp transposed in LDS) ----------------
__global__ __launch_bounds__(256)
void k_ctxp(const float* __restrict__ scores, const float* __restrict__ x,
            float* __restrict__ ctx)
{
    int c0 = blockIdx.x * 256;
    int k0 = blockIdx.y * 64;
    int b  = blockIdx.z;
    const float* A  = scores + ((size_t)b * Kk + k0) * Pp;       // attn [64][1024]
    const float* Bm = x + (size_t)b * Nn * Dd + (size_t)Rr * Dd; // xp [1024][768]

    __shared__ u16 As[2][64][40]  __attribute__((aligned(16)));
    __shared__ u16 Bt[2][256][40] __attribute__((aligned(16)));  // Bt[c][p], XOR-swizzled

    int t = threadIdx.x;
    int lane = t & 63, wv = t >> 6;
    int lr = lane & 15, lg = lane >> 4;
    int sr = t >> 2, sc = (t & 3) * 8;
    int ct = t & 63, pt0 = t >> 6;          // 4x4 transpose tiles: c-tile, p-tile

    f32x4 acc[4][4] = {};
    float4 pa0, pa1, pb[8];

    #define LOADB(d0) do { \
        _Pragma("unroll") \
        for (int tl = 0; tl < 2; tl++) { \
            int pt = pt0 + tl * 4; \
            _Pragma("unroll") \
            for (int u = 0; u < 4; u++) \
                pb[tl * 4 + u] = *(const float4*)(Bm + (size_t)((d0) + pt * 4 + u) * Dd + c0 + ct * 4); \
        } \
    } while(0)
    #define STOREB(buf) do { \
        _Pragma("unroll") \
        for (int tl = 0; tl < 2; tl++) { \
            int pt = pt0 + tl * 4; \
            _Pragma("unroll") \
            for (int i = 0; i < 4; i++) { \
                int cl = ct * 4 + i; \
                int po = (pt * 4) ^ (((cl >> 3) & 3) << 3); \
                union { unsigned u2[2]; ushort4 s4; } w; \
                w.u2[0] = cvt2(((const float*)&pb[tl*4+0])[i], ((const float*)&pb[tl*4+1])[i]); \
                w.u2[1] = cvt2(((const float*)&pb[tl*4+2])[i], ((const float*)&pb[tl*4+3])[i]); \
                *(ushort4*)&Bt[buf][cl][po] = w.s4; \
            } \
        } \
    } while(0)

    pa0 = *(const float4*)(A + (size_t)sr * Pp + sc);
    pa1 = *(const float4*)(A + (size_t)sr * Pp + sc + 4);
    LOADB(0);
    *(bf16x8*)&As[0][sr][sc] = pk8(pa0, pa1);
    STOREB(0);

    int cur = 0;
    for (int it = 0; it < 32; ++it) {
        int d1 = (it + 1) * 32;
        if (it < 31) {
            pa0 = *(const float4*)(A + (size_t)sr * Pp + d1 + sc);
            pa1 = *(const float4*)(A + (size_t)sr * Pp + d1 + sc + 4);
            LOADB(d1);
        }
        __syncthreads();
        bf16x8 af[4], bf[4];
        #pragma unroll
        for (int mt = 0; mt < 4; mt++) af[mt] = *(const bf16x8*)&As[cur][mt * 16 + lr][lg * 8];
        #pragma unroll
        for (int nt = 0; nt < 4; nt++) {
            int row = wv * 64 + nt * 16 + lr;
            bf[nt] = *(const bf16x8*)&Bt[cur][row][(lg ^ ((row >> 3) & 3)) * 8];
        }
        #pragma unroll
        for (int mt = 0; mt < 4; mt++)
            #pragma unroll
            for (int nt = 0; nt < 4; nt++)
                acc[mt][nt] = __builtin_amdgcn_mfma_f32_16x16x32_bf16(af[mt], bf[nt], acc[mt][nt], 0, 0, 0);
        if (it < 31) {
            int nb = cur ^ 1;
            *(bf16x8*)&As[nb][sr][sc] = pk8(pa0, pa1);
            STOREB(nb);
        }
        cur ^= 1;
    }
    float* C = ctx + ((size_t)b * CTX + Rr + k0) * Dd + c0;
    #pragma unroll
    for (int mt = 0; mt < 4; mt++)
        #pragma unroll
        for (int nt = 0; nt < 4; nt++)
            #pragma unroll
            for (int r = 0; r < 4; r++)
                C[(size_t)(mt * 16 + lg * 4 + r) * Dd + wv * 64 + nt * 16 + lr] = acc[mt][nt][r];
    #undef LOADB
    #undef STOREB
}

// ---------------- K4b: copy xreg rows into ctx ----------------
__global__ __launch_bounds__(256)
void k_xreg(const float* __restrict__ x, float* __restrict__ ctx)
{
    int b = blockIdx.x, t = threadIdx.x;
    const float* src = x + (size_t)b * Nn * Dd;
    float* dst = ctx + (size_t)b * CTX * Dd;
    for (int i = t; i < Rr * Dd; i += 256) dst[i] = src[i];
}

// ---------------- K5: kv = ctx @ Wctx + bctx  (bf16 MFMA, fp32 in via cvt, bf16 out) ----------------
__global__ __launch_bounds__(256)
void k_kv(const float* __restrict__ ctx, const float* __restrict__ Wctx,
          const float* __restrict__ bctx, u16* __restrict__ kvb)
{
    int c0 = blockIdx.x * 64;
    int m0 = blockIdx.y * 64;
    int b  = blockIdx.z;
    const float* A = ctx + (size_t)b * CTX * Dd;
    __shared__ u16 as [64][40] __attribute__((aligned(16)));
    __shared__ u16 ws [64][40] __attribute__((aligned(16)));
    int t = threadIdx.x;
    int lane = t & 63, wv = t >> 6;
    int lr = lane & 15, lg = lane >> 4;
    int sr = t >> 2, sc = (t & 3) * 8;
    int wr = t >> 3, wc = (t & 7) * 8;
    int am = m0 + sr; if (am >= CTX) am = CTX - 1;
    f32x4 acc[4] = {};
    for (int d0 = 0; d0 < Dd; d0 += 32) {
        float4 xa = *(const float4*)(A + (size_t)am * Dd + d0 + sc);
        float4 xb = *(const float4*)(A + (size_t)am * Dd + d0 + sc + 4);
        float4 wa = *(const float4*)(Wctx + (size_t)(d0 + wr) * TWO_D + c0 + wc);
        float4 wb = *(const float4*)(Wctx + (size_t)(d0 + wr) * TWO_D + c0 + wc + 4);
        __syncthreads();
        ushort4 x0; x0.x = f2bs(xa.x); x0.y = f2bs(xa.y); x0.z = f2bs(xa.z); x0.w = f2bs(xa.w);
        ushort4 x1; x1.x = f2bs(xb.x); x1.y = f2bs(xb.y); x1.z = f2bs(xb.z); x1.w = f2bs(xb.w);
        *(ushort4*)&as[sr][sc]     = x0;
        *(ushort4*)&as[sr][sc + 4] = x1;
        ws[wc+0][wr] = f2bs(wa.x); ws[wc+1][wr] = f2bs(wa.y);
        ws[wc+2][wr] = f2bs(wa.z); ws[wc+3][wr] = f2bs(wa.w);
        ws[wc+4][wr] = f2bs(wb.x); ws[wc+5][wr] = f2bs(wb.y);
        ws[wc+6][wr] = f2bs(wb.z); ws[wc+7][wr] = f2bs(wb.w);
        __syncthreads();
        bf16x8 a = *(const bf16x8*)&as[wv * 16 + lr][lg * 8];
        #pragma unroll
        for (int nt = 0; nt < 4; nt++) {
            bf16x8 bfr = *(const bf16x8*)&ws[nt * 16 + lr][lg * 8];
            acc[nt] = __builtin_amdgcn_mfma_f32_16x16x32_bf16(a, bfr, acc[nt], 0, 0, 0);
        }
    }
    #pragma unroll
    for (int nt = 0; nt < 4; nt++) {
        float bias = bctx[c0 + nt * 16 + lr];
        #pragma unroll
        for (int r = 0; r < 4; r++) {
            int m = m0 + wv * 16 + lg * 4 + r;
            if (m < CTX)
                kvb[((size_t)b * CTX + m) * TWO_D + c0 + nt * 16 + lr] =
                    f2bs(acc[nt][r] + bias);
        }
    }
}

// ---------------- K6a: q = (x @ Wq) * 0.125 -> bf16 into qy ----------------
__global__ __launch_bounds__(256)
void k_q(const float* __restrict__ x, const u16* __restrict__ WqT,
         u16* __restrict__ q)
{
    int p = blockIdx.x;
    int within = p % 24;
    int ct = within >> 3;
    int rt = (p / 24) * 8 + (within & 7);
    if (rt >= 1029) return;
    int r0 = rt * 64;
    int c0 = ct * 256;

    __shared__ u16 As[2][64][40]  __attribute__((aligned(16)));
    __shared__ u16 Bs[2][256][40] __attribute__((aligned(16)));

    int t = threadIdx.x;
    int lane = t & 63, wv = t >> 6;
    int lr = lane & 15, lg = lane >> 4;
    int sr = t >> 2, sc = (t & 3) * 8;

    const float* xr = x + (size_t)(r0 + sr) * Dd + sc;
    const u16*   wr = WqT + (size_t)(c0 + sr) * Dd + sc;

    f32x4 acc[4][4] = {};
    float4 xa, xb;
    bf16x8 wb0, wb1, wb2, wb3;

    xa = *(const float4*)(xr + 0);
    xb = *(const float4*)(xr + 4);
    wb0 = *(const bf16x8*)(wr + 0 * 64 * Dd);
    wb1 = *(const bf16x8*)(wr + 1 * 64 * Dd);
    wb2 = *(const bf16x8*)(wr + 2 * 64 * Dd);
    wb3 = *(const bf16x8*)(wr + 3 * 64 * Dd);
    {
        bf16x8 av; av[0]=f2bs(xa.x); av[1]=f2bs(xa.y); av[2]=f2bs(xa.z); av[3]=f2bs(xa.w);
        av[4]=f2bs(xb.x); av[5]=f2bs(xb.y); av[6]=f2bs(xb.z); av[7]=f2bs(xb.w);
        *(bf16x8*)&As[0][sr][sc] = av;
        *(bf16x8*)&Bs[0][0*64+sr][sc] = wb0;
        *(bf16x8*)&Bs[0][1*64+sr][sc] = wb1;
        *(bf16x8*)&Bs[0][2*64+sr][sc] = wb2;
        *(bf16x8*)&Bs[0][3*64+sr][sc] = wb3;
    }
    int cur = 0;
    for (int it = 0; it < 24; ++it) {
        int d1 = (it + 1) * 32;
        if (it < 23) {
            xa = *(const float4*)(xr + d1 + 0);
            xb = *(const float4*)(xr + d1 + 4);
            wb0 = *(const bf16x8*)(wr + 0 * 64 * Dd + d1);
            wb1 = *(const bf16x8*)(wr + 1 * 64 * Dd + d1);
            wb2 = *(const bf16x8*)(wr + 2 * 64 * Dd + d1);
            wb3 = *(const bf16x8*)(wr + 3 * 64 * Dd + d1);
        }
        __syncthreads();
        bf16x8 af[4], bf[4];
        #pragma unroll
        for (int mt = 0; mt < 4; mt++) af[mt] = *(const bf16x8*)&As[cur][mt * 16 + lr][lg * 8];
        #pragma unroll
        for (int nt = 0; nt < 4; nt++) bf[nt] = *(const bf16x8*)&Bs[cur][wv * 64 + nt * 16 + lr][lg * 8];
        #pragma unroll
        for (int mt = 0; mt < 4; mt++)
            #pragma unroll
            for (int nt = 0; nt < 4; nt++)
                acc[mt][nt] = __builtin_amdgcn_mfma_f32_16x16x32_bf16(af[mt], bf[nt], acc[mt][nt], 0, 0, 0);
        if (it < 23) {
            bf16x8 av; av[0]=f2bs(xa.x); av[1]=f2bs(xa.y); av[2]=f2bs(xa.z); av[3]=f2bs(xa.w);
            av[4]=f2bs(xb.x); av[5]=f2bs(xb.y); av[6]=f2bs(xb.z); av[7]=f2bs(xb.w);
            int nb = cur ^ 1;
            *(bf16x8*)&As[nb][sr][sc] = av;
            *(bf16x8*)&Bs[nb][0*64+sr][sc] = wb0;
            *(bf16x8*)&Bs[nb][1*64+sr][sc] = wb1;
            *(bf16x8*)&Bs[nb][2*64+sr][sc] = wb2;
            *(bf16x8*)&Bs[nb][3*64+sr][sc] = wb3;
        }
        cur ^= 1;
    }
    #pragma unroll
    for (int mt = 0; mt < 4; mt++)
        #pragma unroll
        for (int nt = 0; nt < 4; nt++)
            #pragma unroll
            for (int r = 0; r < 4; r++)
                q[(size_t)(r0 + mt * 16 + lg * 4 + r) * Dd + c0 + wv * 64 + nt * 16 + lr] =
                    f2bs(acc[mt][nt][r] * 0.125f);
}

// ---------------- K6b: attention; one block = half the n-range of one (b,h) ----------------
// Stage K/V once, loop 8-9 n-tiles of 64 rows. Loop is barrier-free (ps is wave-private).
__global__ __launch_bounds__(256)
void k_attn(const u16* __restrict__ kvb, u16* __restrict__ qy)
{
    int half = blockIdx.x;
    int h  = blockIdx.y;
    int b  = blockIdx.z;
    int t = threadIdx.x;
    int lane = t & 63, wv = t >> 6;
    int lr = lane & 15, lg = lane >> 4;

    __shared__ u16 ks [144][72]      __attribute__((aligned(16)));
    __shared__ u16 vst[64][168]      __attribute__((aligned(16)));
    __shared__ u16 ps [4][16][168]   __attribute__((aligned(16)));

    // ---- stage K (row-major) and V (transposed) once; zero the pads ----
    const u16* kvrow = kvb + (size_t)b * CTX * TWO_D + h * DH;
    for (int e4 = t * 4; e4 < CTX * DH; e4 += 1024) {
        int m = e4 >> 6, dd = e4 & 63;
        *(ushort4*)&ks[m][dd] = *(const ushort4*)(kvrow + (size_t)m * TWO_D + dd);
        ushort4 vv = *(const ushort4*)(kvrow + (size_t)m * TWO_D + Dd + dd);
        vst[dd + 0][m] = vv.x; vst[dd + 1][m] = vv.y;
        vst[dd + 2][m] = vv.z; vst[dd + 3][m] = vv.w;
    }
    for (int i = t; i < 11 * 64; i += 256) ks[133 + (i >> 6)][i & 63] = 0;
    for (int i = t; i < 64 * 27; i += 256) vst[i / 27][133 + i % 27] = 0;
    for (int i = t; i < 64 * 16; i += 256) {
        int rr = i >> 4;
        ps[rr >> 4][rr & 15][144 + (i & 15)] = 0;
    }
    __syncthreads();

    int nt0 = half * 9;
    int nt1 = nt0 + 9; if (nt1 > 17) nt1 = 17;
    const u16* qbase = qy + (size_t)b * Nn * Dd + h * DH;

    // preload q for first tile
    int qn = nt0 * 64 + wv * 16 + lr;
    size_t qoff = (size_t)(qn < Nn ? qn : Nn - 1) * Dd;
    bf16x8 aq0 = *(const bf16x8*)(qbase + qoff + lg * 8);
    bf16x8 aq1 = *(const bf16x8*)(qbase + qoff + 32 + lg * 8);

    for (int nt = nt0; nt < nt1; nt++) {
        int n0 = nt * 64;
        bf16x8 cq0 = aq0, cq1 = aq1;
        if (nt + 1 < nt1) {   // prefetch next q tile
            int q2 = (nt + 1) * 64 + wv * 16 + lr;
            size_t qo2 = (size_t)(q2 < Nn ? q2 : Nn - 1) * Dd;
            aq0 = *(const bf16x8*)(qbase + qo2 + lg * 8);
            aq1 = *(const bf16x8*)(qbase + qo2 + 32 + lg * 8);
        }

        // QK^T
        f32x4 stile[9];
        #pragma unroll
        for (int tn = 0; tn < 9; tn++) {
            bf16x8 bk0 = *(const bf16x8*)&ks[tn * 16 + lr][lg * 8];
            bf16x8 bk1 = *(const bf16x8*)&ks[tn * 16 + lr][32 + lg * 8];
            f32x4 a = {0.f, 0.f, 0.f, 0.f};
            a = __builtin_amdgcn_mfma_f32_16x16x32_bf16(cq0, bk0, a, 0, 0, 0);
            a = __builtin_amdgcn_mfma_f32_16x16x32_bf16(cq1, bk1, a, 0, 0, 0);
            stile[tn] = a;
        }

        // softmax per output row
        #pragma unroll
        for (int r = 0; r < 4; r++) {
            float m_ = -3.4e38f;
            #pragma unroll
            for (int tn = 0; tn < 9; tn++) {
                float v = stile[tn][r];
                if (tn == 8 && lr >= 5) v = -3.4e38f;
                m_ = fmaxf(m_, v);
            }
            m_ = fmaxf(m_, __shfl_xor(m_, 1));
            m_ = fmaxf(m_, __shfl_xor(m_, 2));
            m_ = fmaxf(m_, __shfl_xor(m_, 4));
            m_ = fmaxf(m_, __shfl_xor(m_, 8));
            float pv[9];
            float s_ = 0.f;
            #pragma unroll
            for (int tn = 0; tn < 9; tn++) {
                float v = stile[tn][r];
                v = (tn == 8 && lr >= 5) ? 0.f : __expf(v - m_);
                pv[tn] = v; s_ += v;
            }
            s_ += __shfl_xor(s_, 1);
            s_ += __shfl_xor(s_, 2);
            s_ += __shfl_xor(s_, 4);
            s_ += __shfl_xor(s_, 8);
            float inv = 1.f / s_;
            #pragma unroll
            for (int tn = 0; tn < 9; tn++)
                ps[wv][lg * 4 + r][tn * 16 + lr] = f2bs(pv[tn] * inv);
        }
        // ps is wave-private: compiler orders the ds_write->ds_read (same LDS object)

        // PV
        f32x4 yacc[4] = {};
        #pragma unroll
        for (int kk = 0; kk < 5; kk++) {
            bf16x8 ap = *(const bf16x8*)&ps[wv][lr][kk * 32 + lg * 8];
            #pragma unroll
            for (int td = 0; td < 4; td++) {
                bf16x8 bv = *(const bf16x8*)&vst[td * 16 + lr][kk * 32 + lg * 8];
                yacc[td] = __builtin_amdgcn_mfma_f32_16x16x32_bf16(ap, bv, yacc[td], 0, 0, 0);
            }
        }

        // store y (overwrites this block's q rows; q already consumed)
        #pragma unroll
        for (int td = 0; td < 4; td++)
            #pragma unroll
            for (int r = 0; r < 4; r++) {
                int gn = n0 + wv * 16 + lg * 4 + r;
                if (gn < Nn)
                    qy[((size_t)b * Nn + gn) * Dd + h * DH + td * 16 + lr] = f2bs(yacc[td][r]);
            }
    }
}

// ---------------- K7: out = y @ Wout + bout ----------------
__global__ __launch_bounds__(256)
void k_out(const u16* __restrict__ y, const u16* __restrict__ WoT,
           const float* __restrict__ bout, float* __restrict__ outp)
{
    int p = blockIdx.x;
    int within = p % 24;
    int ct = within >> 3;
    int rt = (p / 24) * 8 + (within & 7);
    if (rt >= 1029) return;
    int r0 = rt * 64;
    int c0 = ct * 256;

    __shared__ u16 As[2][64][40]  __attribute__((aligned(16)));
    __shared__ u16 Bs[2][256][40] __attribute__((aligned(16)));

    int t = threadIdx.x;
    int lane = t & 63, wv = t >> 6;
    int lr = lane & 15, lg = lane >> 4;
    int sr = t >> 2, sc = (t & 3) * 8;

    const u16* yr = y + (size_t)(r0 + sr) * Dd + sc;
    const u16* wr = WoT + (size_t)(c0 + sr) * Dd + sc;

    f32x4 acc[4][4] = {};
    bf16x8 av, wb0, wb1, wb2, wb3;

    av  = *(const bf16x8*)(yr + 0);
    wb0 = *(const bf16x8*)(wr + 0 * 64 * Dd);
    wb1 = *(const bf16x8*)(wr + 1 * 64 * Dd);
    wb2 = *(const bf16x8*)(wr + 2 * 64 * Dd);
    wb3 = *(const bf16x8*)(wr + 3 * 64 * Dd);
    *(bf16x8*)&As[0][sr][sc] = av;
    *(bf16x8*)&Bs[0][0*64+sr][sc] = wb0;
    *(bf16x8*)&Bs[0][1*64+sr][sc] = wb1;
    *(bf16x8*)&Bs[0][2*64+sr][sc] = wb2;
    *(bf16x8*)&Bs[0][3*64+sr][sc] = wb3;

    int cur = 0;
    for (int it = 0; it < 24; ++it) {
        int d1 = (it + 1) * 32;
        if (it < 23) {
            av  = *(const bf16x8*)(yr + d1);
            wb0 = *(const bf16x8*)(wr + 0 * 64 * Dd + d1);
            wb1 = *(const bf16x8*)(wr + 1 * 64 * Dd + d1);
            wb2 = *(const bf16x8*)(wr + 2 * 64 * Dd + d1);
            wb3 = *(const bf16x8*)(wr + 3 * 64 * Dd + d1);
        }
        __syncthreads();
        bf16x8 af[4], bf[4];
        #pragma unroll
        for (int mt = 0; mt < 4; mt++) af[mt] = *(const bf16x8*)&As[cur][mt * 16 + lr][lg * 8];
        #pragma unroll
        for (int nt = 0; nt < 4; nt++) bf[nt] = *(const bf16x8*)&Bs[cur][wv * 64 + nt * 16 + lr][lg * 8];
        #pragma unroll
        for (int mt = 0; mt < 4; mt++)
            #pragma unroll
            for (int nt = 0; nt < 4; nt++)
                acc[mt][nt] = __builtin_amdgcn_mfma_f32_16x16x32_bf16(af[mt], bf[nt], acc[mt][nt], 0, 0, 0);
        if (it < 23) {
            int nb = cur ^ 1;
            *(bf16x8*)&As[nb][sr][sc] = av;
            *(bf16x8*)&Bs[nb][0*64+sr][sc] = wb0;
            *(bf16x8*)&Bs[nb][1*64+sr][sc] = wb1;
            *(bf16x8*)&Bs[nb][2*64+sr][sc] = wb2;
            *(bf16x8*)&Bs[nb][3*64+sr][sc] = wb3;
        }
        cur ^= 1;
    }
    #pragma unroll
    for (int nt = 0; nt < 4; nt++) {
        float bias = bout[c0 + wv * 64 + nt * 16 + lr];
        #pragma unroll
        for (int mt = 0; mt < 4; mt++)
            #pragma unroll
            for (int r = 0; r < 4; r++)
                outp[(size_t)(r0 + mt * 16 + lg * 4 + r) * Dd + c0 + wv * 64 + nt * 16 + lr] =
                    acc[mt][nt][r] + bias;
    }
}

extern "C" void kernel_launch(void* const* d_in, const int* in_sizes, int n_in,
                              void* d_out, int out_size, void* d_ws, size_t ws_size,
                              hipStream_t stream)
{
    const float* x    = (const float*)d_in[0];
    const float* Qb   = (const float*)d_in[1];
    const float* Wq   = (const float*)d_in[2];
    const float* Wctx = (const float*)d_in[3];
    const float* bctx = (const float*)d_in[4];
    const float* Wout = (const float*)d_in[5];
    const float* bout = (const float*)d_in[6];
    const float* cent = (const float*)d_in[7];

    float* out     = (float*)d_out;
    float* out_cls = out + (size_t)Bc * Nn * Dd;
    float* out_idx = out_cls + (size_t)Bc * Dd;

    const size_t SC_B  = (size_t)Bc * Kk * Pp * 4;   // 33,554,432
    const size_t CTX_B = (size_t)Bc * CTX * Dd * 4;  // 26,148,864
    const size_t Y_B   = (size_t)Bc * Nn * Dd * 2;   // 101,154,816
    const size_t NEED  = 1024 + SC_B + CTX_B + Y_B;  // 160,859,136
    if (ws_size < NEED) return;

    char* w = (char*)d_ws;
    int*   idx_i  = (int*)w;
    float* scores = (float*)(w + 1024);
    u16*   kvb    = (u16*)(w + 1024);               // reuses scores region after K4
    float* ctx    = (float*)(w + 1024 + SC_B);
    u16*   qy     = (u16*)(w + 1024 + SC_B + CTX_B);

    u16* WqT   = (u16*)out;   // dead until k_out
    u16* WoutT = (u16*)ctx;   // ctx dead after k_kv

    k_cls    <<<Bc, 256, 0, stream>>>(x, cent, out_cls, out_idx, idx_i);
    k_prep   <<<dim3(12, 12), 256, 0, stream>>>(Wq, WqT, Dd, Dd);
    k_q      <<<3096, 256, 0, stream>>>(x, WqT, qy);
    k_scores <<<dim3(4, 2, Bc), 256, 0, stream>>>(x, Qb, idx_i, scores);
    k_softmax<<<Bc * Kk, 256, 0, stream>>>(scores);
    k_ctxp   <<<dim3(3, 2, Bc), 256, 0, stream>>>(scores, x, ctx);
    k_xreg   <<<Bc, 256, 0, stream>>>(x, ctx);
    k_kv     <<<dim3(24, 3, Bc), 256, 0, stream>>>(ctx, Wctx, bctx, kvb);
    k_prep   <<<dim3(12, 12), 256, 0, stream>>>(Wout, WoutT, Dd, Dd);
    k_attn   <<<dim3(2, Hh, Bc), 256, 0, stream>>>(kvb, qy);
    k_out    <<<3096, 256, 0, stream>>>(qy, WoutT, bout, out);
}